// Round 12
// baseline (122.485 us; speedup 1.0000x reference)
//
#include <hip/hip_runtime.h>
#include <stdint.h>

typedef __attribute__((ext_vector_type(4))) int i32x4;

// BinaryConv: out = sign(conv2d(sign(x), sign(w), pad=1) + bias)
// i8 MFMA implicit GEMM. Tile 128 pixels x 256 out-ch, BK=64, 36 K-tiles.
// R12: m201-style 4-phase interleave inside each K-tile + s_setprio (T3+T5);
// sync skeleton (STAGE -> vmcnt(6) -> barrier ... end-barrier) identical to R11.

#define NB 32
#define CC 256
#define HH 56
#define WW 56
#define OO 256
#define PH 58
#define PW 58
#define SS (HH*WW)      // 3136
#define KTOT 2304

// ---- async global->LDS, 16B per lane; dest = wave-uniform base + lane*16 -----------
__device__ __forceinline__ void gload16(const void* g, void* l) {
    const __attribute__((address_space(1))) void* gp =
        reinterpret_cast<const __attribute__((address_space(1))) void*>(
            reinterpret_cast<uintptr_t>(g));
    __attribute__((address_space(3))) void* lp =
        reinterpret_cast<__attribute__((address_space(3))) void*>(
            static_cast<uintptr_t>(static_cast<uint32_t>(reinterpret_cast<uintptr_t>(l))));
    __builtin_amdgcn_global_load_lds(gp, lp, 16, 0, 0);
}

#define WAITVM(N) asm volatile("s_waitcnt vmcnt(" #N ")" ::: "memory")
#define WAITLGKM0() asm volatile("s_waitcnt lgkmcnt(0)" ::: "memory")

// ============================ pack kernels ==========================================

// xs: [n][ph][pw][c] i8, border rows/cols = 0. Reads vectorized float4 x14 per row.
__global__ __launch_bounds__(256) void pack_xs_kernel(const float* __restrict__ x,
                                                      int8_t* __restrict__ xs) {
    int c  = threadIdx.x;
    int ph = blockIdx.x;
    int n  = blockIdx.y;
    int8_t* dst = xs + (((size_t)n * PH + ph) * PW) * 256 + c;
    if (ph == 0 || ph == PH - 1) {
        for (int pw = 0; pw < PW; ++pw) dst[(size_t)pw * 256] = 0;
        return;
    }
    int h = ph - 1;
    const float4* src4 = (const float4*)(x + ((size_t)(n * CC + c) * HH + h) * WW);
    float4 rowv[14];
#pragma unroll
    for (int i = 0; i < 14; ++i) rowv[i] = src4[i];
    dst[0] = 0;
    dst[(size_t)(PW - 1) * 256] = 0;
    const float* rv = (const float*)rowv;
#pragma unroll
    for (int w = 0; w < 56; ++w) {
        float v = rv[w];
        int8_t s = (v > 0.f) ? 1 : ((v < 0.f) ? -1 : 0);
        dst[(size_t)(w + 1) * 256] = s;
    }
}

// wsB: [o][t][c] i8 (t = kh*3+kw)
__global__ __launch_bounds__(256) void pack_wsB_kernel(const float* __restrict__ wgt,
                                                       int8_t* __restrict__ wsB) {
    int c = threadIdx.x;
    int o = blockIdx.x;
    const float* src = wgt + ((size_t)o * CC + c) * 9;
#pragma unroll
    for (int t = 0; t < 9; ++t) {
        float v = src[t];
        int8_t s = (v > 0.f) ? 1 : ((v < 0.f) ? -1 : 0);
        wsB[(size_t)o * KTOT + t * 256 + c] = s;
    }
}

// ============================ MFMA GEMM =============================================
// Block = 4 waves (2M x 2N), tile 128 pixels x 256 out-ch, BK=64. 36 K-tiles.
// LDS: A[2][128*64]=16KB + B[2][256*64]=32KB = 48KB dbuf. STAGE = 6 gload16/thread.
// Per tile: STAGE(next) -> vmcnt(6) -> barrier -> 4 phases of
//   { ds_read 2 B-frags (+4 A-frags in P0); lgkmcnt(0); setprio(1) 8 MFMA setprio(0);
//     barrier }  -- phase p+1's reads issue while phase p's MFMAs drain (T3+T5).
// Counted vmcnt keeps next tile's 6 loads in flight across barriers (T4).
// Swizzle (bit-exact since R9): LDS[row][chunk]=GLOBAL[row][chunk^((row>>1)&3)].

#define STAGE(BUF, KT) do {                                                  \
    const int _t = (KT) >> 2, _q = (KT) & 3;                                 \
    const uint32_t _at = (uint32_t)(((_t / 3) * PW + (_t % 3)) * 256 + _q * 64); \
    const uint32_t _bt = (uint32_t)(_t * 256 + _q * 64);                     \
    gload16(xs + (apb0 + _at), &Asm[BUF][wid * 1024]);                       \
    gload16(xs + (apb1 + _at), &Asm[BUF][4096 + wid * 1024]);                \
    gload16(wsB + (bpb0 + _bt), &Bsm[BUF][wid * 1024]);                      \
    gload16(wsB + (bpb1 + _bt), &Bsm[BUF][4096 + wid * 1024]);               \
    gload16(wsB + (bpb2 + _bt), &Bsm[BUF][8192 + wid * 1024]);               \
    gload16(wsB + (bpb3 + _bt), &Bsm[BUF][12288 + wid * 1024]);              \
} while (0)

#define MFMA8(Q, B0, B1) do {                                                \
    _Pragma("unroll")                                                        \
    for (int _s = 0; _s < 4; ++_s) {                                         \
        acc[_s][2*(Q)]   = __builtin_amdgcn_mfma_i32_16x16x64_i8(af[_s], B0, acc[_s][2*(Q)],   0, 0, 0); \
        acc[_s][2*(Q)+1] = __builtin_amdgcn_mfma_i32_16x16x64_i8(af[_s], B1, acc[_s][2*(Q)+1], 0, 0, 0); \
    }                                                                        \
} while (0)

// one K-tile, 4-phase interleave
#define TILE_PHASES(CUR) do {                                                \
    const int8_t* _Ab = &Asm[CUR][0];                                        \
    const int8_t* _Bb = &Bsm[CUR][0];                                        \
    i32x4 af[4], b0, b1;                                                     \
    /* P0 */                                                                 \
    af[0] = *(const i32x4*)(_Ab + swzA[0]);                                  \
    af[1] = *(const i32x4*)(_Ab + swzA[1]);                                  \
    af[2] = *(const i32x4*)(_Ab + swzA[2]);                                  \
    af[3] = *(const i32x4*)(_Ab + swzA[3]);                                  \
    b0 = *(const i32x4*)(_Bb + swzB[0]);                                     \
    b1 = *(const i32x4*)(_Bb + swzB[1]);                                     \
    WAITLGKM0(); __builtin_amdgcn_sched_barrier(0);                          \
    __builtin_amdgcn_s_setprio(1); MFMA8(0, b0, b1); __builtin_amdgcn_s_setprio(0); \
    __builtin_amdgcn_s_barrier();                                            \
    /* P1 */                                                                 \
    b0 = *(const i32x4*)(_Bb + swzB[2]);                                     \
    b1 = *(const i32x4*)(_Bb + swzB[3]);                                     \
    WAITLGKM0(); __builtin_amdgcn_sched_barrier(0);                          \
    __builtin_amdgcn_s_setprio(1); MFMA8(1, b0, b1); __builtin_amdgcn_s_setprio(0); \
    __builtin_amdgcn_s_barrier();                                            \
    /* P2 */                                                                 \
    b0 = *(const i32x4*)(_Bb + swzB[4]);                                     \
    b1 = *(const i32x4*)(_Bb + swzB[5]);                                     \
    WAITLGKM0(); __builtin_amdgcn_sched_barrier(0);                          \
    __builtin_amdgcn_s_setprio(1); MFMA8(2, b0, b1); __builtin_amdgcn_s_setprio(0); \
    __builtin_amdgcn_s_barrier();                                            \
    /* P3 */                                                                 \
    b0 = *(const i32x4*)(_Bb + swzB[6]);                                     \
    b1 = *(const i32x4*)(_Bb + swzB[7]);                                     \
    WAITLGKM0(); __builtin_amdgcn_sched_barrier(0);                          \
    __builtin_amdgcn_s_setprio(1); MFMA8(3, b0, b1); __builtin_amdgcn_s_setprio(0); \
    __builtin_amdgcn_s_barrier();                                            \
} while (0)

__global__ __launch_bounds__(256, 2) void bconv_mfma_kernel(const int8_t* __restrict__ xs,
                                                            const int8_t* __restrict__ wsB,
                                                            const float* __restrict__ bias,
                                                            float* __restrict__ out) {
    __shared__ __align__(16) int8_t Asm[2][128 * 64];   // 16 KB
    __shared__ __align__(16) int8_t Bsm[2][256 * 64];   // 32 KB

    const int m   = blockIdx.x;            // 0..783 M-tile (BN = whole N)
    const int tid = threadIdx.x;
    const int l   = tid & 63;
    const int wid = tid >> 6;
    const int lg  = l >> 4;                // k-group 0..3
    const int lr  = l & 15;                // row (A) / col (B,C)
    const int wm  = wid & 1, wn = wid >> 1;

    const int M0 = m * 128;

    // ---- staging addresses: thread handles row i*64 + (tid>>2), chunk tid&3 --------
    const int srow0 = tid >> 2;
    const int g16   = (((tid & 3) ^ ((tid >> 3) & 3)) << 4);
    uint32_t apb0, apb1, bpb0, bpb1, bpb2, bpb3;
    {
        int p0 = M0 + srow0;
        int n0 = p0 / SS, sp0 = p0 - n0 * SS, h0 = sp0 / WW, w0 = sp0 - h0 * WW;
        apb0 = (uint32_t)(((n0 * PH + h0) * PW + w0) * 256 + g16);
        int p1 = M0 + 64 + srow0;
        int n1 = p1 / SS, sp1 = p1 - n1 * SS, h1 = sp1 / WW, w1 = sp1 - h1 * WW;
        apb1 = (uint32_t)(((n1 * PH + h1) * PW + w1) * 256 + g16);
        bpb0 = (uint32_t)((srow0) * KTOT + g16);
        bpb1 = (uint32_t)((64 + srow0) * KTOT + g16);
        bpb2 = (uint32_t)((128 + srow0) * KTOT + g16);
        bpb3 = (uint32_t)((192 + srow0) * KTOT + g16);
    }

    // ---- ds_read offsets (swizzled) ------------------------------------------------
    const int swz16 = ((lg ^ ((lr >> 1) & 3)) << 4);
    int swzA[4], swzB[8];
#pragma unroll
    for (int s = 0; s < 4; ++s) swzA[s] = (wm * 64 + s * 16 + lr) * 64 + swz16;
#pragma unroll
    for (int u = 0; u < 8; ++u) swzB[u] = (wn * 128 + u * 16 + lr) * 64 + swz16;

    i32x4 acc[4][8];
#pragma unroll
    for (int s = 0; s < 4; ++s)
#pragma unroll
        for (int u = 0; u < 8; ++u)
            acc[s][u] = (i32x4){0, 0, 0, 0};

    // ---- K-loop: 36 tiles, dbuf, counted vmcnt, 4-phase interleave -----------------
    STAGE(0, 0);
    int cur = 0;
#pragma unroll 1
    for (int kt = 0; kt < 35; ++kt) {
        STAGE(cur ^ 1, kt + 1);            // 12 outstanding
        WAITVM(6);                         // tile kt landed; kt+1 stays in flight
        __builtin_amdgcn_s_barrier();      // buf cur staged for ALL waves
        TILE_PHASES(cur);                  // 4 phases; ends with barrier
        cur ^= 1;
    }
    WAITVM(0);
    __builtin_amdgcn_s_barrier();
    TILE_PHASES(cur);

    // ---- epilogue (bit-exact mapping proven R6/R8/R9/R10/R11) ----------------------
    float bo[8];
#pragma unroll
    for (int u = 0; u < 8; ++u) bo[u] = bias[wn * 128 + u * 16 + lr];

#pragma unroll
    for (int s = 0; s < 4; ++s) {
        int pst = M0 + wm * 64 + s * 16 + lg * 4;
        int n   = pst / SS;
        int sp  = pst - n * SS;
#pragma unroll
        for (int u = 0; u < 8; ++u) {
            i32x4 a = acc[s][u];
            int o = wn * 128 + u * 16 + lr;
            float v0 = (float)a.x + bo[u];
            float v1 = (float)a.y + bo[u];
            float v2 = (float)a.z + bo[u];
            float v3 = (float)a.w + bo[u];
            float4 r4;
            r4.x = (v0 > 0.f) ? 1.f : ((v0 < 0.f) ? -1.f : 0.f);
            r4.y = (v1 > 0.f) ? 1.f : ((v1 < 0.f) ? -1.f : 0.f);
            r4.z = (v2 > 0.f) ? 1.f : ((v2 < 0.f) ? -1.f : 0.f);
            r4.w = (v3 > 0.f) ? 1.f : ((v3 < 0.f) ? -1.f : 0.f);
            *(float4*)(out + ((size_t)(n * OO + o)) * SS + sp) = r4;
        }
    }
}

// ============================ fallback popcount path (R4, 163 us) ===================

#define SPAD (PH*PW)
#define CWN  4

__global__ __launch_bounds__(256) void pack_x_kernel(const float* __restrict__ x,
                                                     uint64_t* __restrict__ px) {
    int tid = threadIdx.x;
    int sp  = blockIdx.x * 256 + tid;
    int cw  = blockIdx.y;
    int n   = blockIdx.z;
    if (sp >= SPAD) return;
    int ph = sp / PW, pw_ = sp % PW;
    uint64_t* dst = px + (((size_t)n * CWN + cw) * SPAD + sp);
    if (ph == 0 || ph == PH - 1 || pw_ == 0 || pw_ == PW - 1) { *dst = 0ull; return; }
    int h = ph - 1, w = pw_ - 1;
    const float* src = x + ((size_t)(n * CC + cw * 64)) * SS + (h * WW + w);
    uint32_t lo = 0u, hi = 0u;
#pragma unroll
    for (int j = 0; j < 32; ++j) { float v = src[(size_t)j * SS];        lo |= (v > 0.0f ? 1u : 0u) << j; }
#pragma unroll
    for (int j = 0; j < 32; ++j) { float v = src[(size_t)(j + 32) * SS]; hi |= (v > 0.0f ? 1u : 0u) << j; }
    *dst = ((uint64_t)hi << 32) | (uint64_t)lo;
}

__global__ __launch_bounds__(256) void pack_w_kernel(const float* __restrict__ wgt,
                                                     uint64_t* __restrict__ pwb) {
    int lane = threadIdx.x & 63;
    int wave = threadIdx.x >> 6;
    int wi   = blockIdx.x * 4 + wave;
    if (wi >= OO * 9 * CWN) return;
    int o = wi / 36, rem = wi % 36, t = rem >> 2, cw = rem & 3;
    int c = cw * 64 + lane;
    float v = wgt[(size_t)(o * CC + c) * 9 + t];
    uint64_t m = __ballot(v > 0.0f);
    if (lane == 0) pwb[wi] = m;
}

__global__ __launch_bounds__(256) void build_k_kernel(const uint64_t* __restrict__ pwb,
                                                      int* __restrict__ ktab) {
    int o = threadIdx.x;
    int pops[9];
#pragma unroll
    for (int t = 0; t < 9; ++t) {
        int p = 0;
#pragma unroll
        for (int cw = 0; cw < 4; ++cw) p += __popcll(pwb[o * 36 + t * 4 + cw]);
        pops[t] = p;
    }
#pragma unroll
    for (int cls = 0; cls < 9; ++cls) {
        int vf = cls / 3, hf = cls % 3;
        int K = 9 * CC;
#pragma unroll
        for (int t = 0; t < 9; ++t) {
            int r = t / 3, k = t % 3;
            bool inv = (vf == 1 && r == 0) || (vf == 2 && r == 2) ||
                       (hf == 1 && k == 0) || (hf == 2 && k == 2);
            if (inv) K -= (CC - 2 * pops[t]);
        }
        ktab[cls * OO + o] = K;
    }
}

__global__ __launch_bounds__(256, 4) void bconv_kernel(const uint64_t* __restrict__ px,
                                                       const uint64_t* __restrict__ pwb,
                                                       const int* __restrict__ ktab,
                                                       const float* __restrict__ bias,
                                                       float* __restrict__ out) {
    int g = blockIdx.x * 256 + threadIdx.x;
    int n = g / SS;
    int sid = g - n * SS;
    int obase = blockIdx.y * 32;
    int h = sid / WW, w = sid - h * WW;
    int vf = (h == 0) ? 1 : ((h == HH - 1) ? 2 : 0);
    int hf = (w == 0) ? 1 : ((w == WW - 1) ? 2 : 0);
    const int* krow = ktab + (vf * 3 + hf) * OO + obase;
    const uint64_t* pb = px + (size_t)n * CWN * SPAD + h * PW + w;
    const uint32_t* wb = (const uint32_t*)pwb + (size_t)obase * 72;
    uint32_t acc[32];
#pragma unroll
    for (int i = 0; i < 32; ++i) acc[i] = 0u;
#pragma unroll 1
    for (int r = 0; r < 3; ++r) {
#pragma unroll 1
        for (int k = 0; k < 3; ++k) {
            int off = r * PW + k;
            uint64_t q0 = pb[off];
            uint64_t q1 = pb[SPAD + off];
            uint64_t q2 = pb[2 * SPAD + off];
            uint64_t q3 = pb[3 * SPAD + off];
            uint32_t pa0 = (uint32_t)q0, pa1 = (uint32_t)(q0 >> 32);
            uint32_t pa2 = (uint32_t)q1, pa3 = (uint32_t)(q1 >> 32);
            uint32_t pa4 = (uint32_t)q2, pa5 = (uint32_t)(q2 >> 32);
            uint32_t pa6 = (uint32_t)q3, pa7 = (uint32_t)(q3 >> 32);
            int t8 = (r * 3 + k) * 8;
#pragma unroll
            for (int oi = 0; oi < 32; ++oi) {
                const uint32_t* wv = wb + oi * 72 + t8;
                uint32_t a = acc[oi];
                a = __popc(pa0 ^ wv[0]) + a;
                a = __popc(pa1 ^ wv[1]) + a;
                a = __popc(pa2 ^ wv[2]) + a;
                a = __popc(pa3 ^ wv[3]) + a;
                a = __popc(pa4 ^ wv[4]) + a;
                a = __popc(pa5 ^ wv[5]) + a;
                a = __popc(pa6 ^ wv[6]) + a;
                a = __popc(pa7 ^ wv[7]) + a;
                acc[oi] = a;
            }
        }
    }
    float* orow = out + ((size_t)(n * OO + obase)) * SS + sid;
#pragma unroll
    for (int oi = 0; oi < 32; ++oi) {
        int s = krow[oi] - 2 * (int)acc[oi];
        float v = (float)s + bias[obase + oi];
        float res = (v > 0.0f) ? 1.0f : ((v < 0.0f) ? -1.0f : 0.0f);
        orow[(size_t)oi * SS] = res;
    }
}

// ============================ launch ================================================

extern "C" void kernel_launch(void* const* d_in, const int* in_sizes, int n_in,
                              void* d_out, int out_size, void* d_ws, size_t ws_size,
                              hipStream_t stream) {
    const float* x    = (const float*)d_in[0];
    const float* wgt  = (const float*)d_in[1];
    const float* bias = (const float*)d_in[2];
    float* out = (float*)d_out;

    const size_t wsB_bytes = (size_t)OO * KTOT;                 // 589,824
    const size_t xs_bytes  = (size_t)NB * PH * PW * 256;        // 27,557,888
    if (ws_size >= wsB_bytes + xs_bytes) {
        int8_t* wsB = (int8_t*)d_ws;
        int8_t* xs  = (int8_t*)d_ws + wsB_bytes;
        pack_xs_kernel<<<dim3(PH, NB), 256, 0, stream>>>(x, xs);
        pack_wsB_kernel<<<dim3(OO), 256, 0, stream>>>(wgt, wsB);
        const int n_blocks = NB * SS / 128;                     // 784 (BN = whole N)
        bconv_mfma_kernel<<<dim3(n_blocks), 256, 0, stream>>>(xs, wsB, bias, out);
    } else {
        // fallback: proven popcount path (R4)
        size_t px_bytes = (size_t)NB * CWN * SPAD * 8;
        size_t pw_off   = px_bytes;
        size_t pw_bytes = (size_t)OO * 9 * CWN * 8;
        size_t k_off    = pw_off + pw_bytes;
        uint64_t* px  = (uint64_t*)d_ws;
        uint64_t* pwb = (uint64_t*)((char*)d_ws + pw_off);
        int*      kt  = (int*)((char*)d_ws + k_off);
        dim3 gpx((SPAD + 255) / 256, CWN, NB);
        pack_x_kernel<<<gpx, 256, 0, stream>>>(x, px);
        int nwords = OO * 9 * CWN;
        pack_w_kernel<<<dim3((nwords + 3) / 4), 256, 0, stream>>>(wgt, pwb);
        build_k_kernel<<<dim3(1), 256, 0, stream>>>(pwb, kt);
        dim3 gcv(NB * SS / 256, OO / 32, 1);
        bconv_kernel<<<gcv, 256, 0, stream>>>(px, pwb, kt, bias, out);
    }
}

// Round 13
// 119.275 us; speedup vs baseline: 1.0269x; 1.0269x over previous
//
#include <hip/hip_runtime.h>
#include <stdint.h>

typedef __attribute__((ext_vector_type(4))) int i32x4;

// BinaryConv: out = sign(conv2d(sign(x), sign(w), pad=1) + bias)
// i8 MFMA implicit GEMM. Tile 128 pixels x 256 out-ch, BK=64, 36 K-tiles.
// R13: 8-wave (512-thread) blocks, wave = 64x64 -> acc[4][4] (64 regs), VGPR<=128
// => 4 waves/SIMD (2 resident blocks/CU). R11's proven monolithic 2-barrier schedule;
// cross-block TLP now hides stage/barrier/ds_read latency (R12 lesson: 1 wave/SIMD
// can hide nothing regardless of phase structure).

#define NB 32
#define CC 256
#define HH 56
#define WW 56
#define OO 256
#define PH 58
#define PW 58
#define SS (HH*WW)      // 3136
#define KTOT 2304

// ---- async global->LDS, 16B per lane; dest = wave-uniform base + lane*16 -----------
__device__ __forceinline__ void gload16(const void* g, void* l) {
    const __attribute__((address_space(1))) void* gp =
        reinterpret_cast<const __attribute__((address_space(1))) void*>(
            reinterpret_cast<uintptr_t>(g));
    __attribute__((address_space(3))) void* lp =
        reinterpret_cast<__attribute__((address_space(3))) void*>(
            static_cast<uintptr_t>(static_cast<uint32_t>(reinterpret_cast<uintptr_t>(l))));
    __builtin_amdgcn_global_load_lds(gp, lp, 16, 0, 0);
}

#define WAITVM(N) asm volatile("s_waitcnt vmcnt(" #N ")" ::: "memory")
#define WAITLGKM0() asm volatile("s_waitcnt lgkmcnt(0)" ::: "memory")

// ============================ pack kernels ==========================================

// xs: [n][ph][pw][c] i8, border rows/cols = 0. Reads vectorized float4 x14 per row.
__global__ __launch_bounds__(256) void pack_xs_kernel(const float* __restrict__ x,
                                                      int8_t* __restrict__ xs) {
    int c  = threadIdx.x;
    int ph = blockIdx.x;
    int n  = blockIdx.y;
    int8_t* dst = xs + (((size_t)n * PH + ph) * PW) * 256 + c;
    if (ph == 0 || ph == PH - 1) {
        for (int pw = 0; pw < PW; ++pw) dst[(size_t)pw * 256] = 0;
        return;
    }
    int h = ph - 1;
    const float4* src4 = (const float4*)(x + ((size_t)(n * CC + c) * HH + h) * WW);
    float4 rowv[14];
#pragma unroll
    for (int i = 0; i < 14; ++i) rowv[i] = src4[i];
    dst[0] = 0;
    dst[(size_t)(PW - 1) * 256] = 0;
    const float* rv = (const float*)rowv;
#pragma unroll
    for (int w = 0; w < 56; ++w) {
        float v = rv[w];
        int8_t s = (v > 0.f) ? 1 : ((v < 0.f) ? -1 : 0);
        dst[(size_t)(w + 1) * 256] = s;
    }
}

// wsB: [o][t][c] i8 (t = kh*3+kw)
__global__ __launch_bounds__(256) void pack_wsB_kernel(const float* __restrict__ wgt,
                                                       int8_t* __restrict__ wsB) {
    int c = threadIdx.x;
    int o = blockIdx.x;
    const float* src = wgt + ((size_t)o * CC + c) * 9;
#pragma unroll
    for (int t = 0; t < 9; ++t) {
        float v = src[t];
        int8_t s = (v > 0.f) ? 1 : ((v < 0.f) ? -1 : 0);
        wsB[(size_t)o * KTOT + t * 256 + c] = s;
    }
}

// ============================ MFMA GEMM =============================================
// Block = 8 waves (2M x 4N), 512 threads. Tile 128 px x 256 ch, BK=64. 36 K-tiles.
// LDS: A[2][128*64]=16KB + B[2][256*64]=32KB = 48KB dbuf; STAGE = 3 gload16/thread
// (1 A chunk + 2 B chunks; 1536 chunks / 512 threads). Counted vmcnt(3) keeps the
// next tile's loads in flight across the barrier (T4). Swizzle (bit-exact since R9):
// LDS[row][chunk] = GLOBAL[row][chunk ^ ((row>>1)&3)]; the XOR term is invariant
// under the +128-row shift (128/2 % 4 == 0), so one g16 serves A and both B halves.

#define STAGE(BUF, KT) do {                                                  \
    const int _t = (KT) >> 2, _q = (KT) & 3;                                 \
    const uint32_t _at = (uint32_t)(((_t / 3) * PW + (_t % 3)) * 256 + _q * 64); \
    const uint32_t _bt = (uint32_t)(_t * 256 + _q * 64);                     \
    gload16(xs + (apb0 + _at), &Asm[BUF][wid * 1024]);                       \
    gload16(wsB + (bpb0 + _bt), &Bsm[BUF][wid * 1024]);                      \
    gload16(wsB + (bpb1 + _bt), &Bsm[BUF][8192 + wid * 1024]);               \
} while (0)

#define COMPUTE(BUF) do {                                                    \
    const int8_t* _Ab = &Asm[BUF][0];                                        \
    const int8_t* _Bb = &Bsm[BUF][0];                                        \
    i32x4 af[4], bf[4];                                                      \
    _Pragma("unroll")                                                        \
    for (int _s = 0; _s < 4; ++_s) af[_s] = *(const i32x4*)(_Ab + swzA[_s]); \
    _Pragma("unroll")                                                        \
    for (int _u = 0; _u < 4; ++_u) bf[_u] = *(const i32x4*)(_Bb + swzB[_u]); \
    WAITLGKM0();                                                             \
    __builtin_amdgcn_sched_barrier(0);                                      \
    _Pragma("unroll")                                                        \
    for (int _s = 0; _s < 4; ++_s) {                                         \
        _Pragma("unroll")                                                    \
        for (int _u = 0; _u < 4; ++_u)                                       \
            acc[_s][_u] = __builtin_amdgcn_mfma_i32_16x16x64_i8(af[_s], bf[_u], acc[_s][_u], 0, 0, 0); \
    }                                                                        \
} while (0)

__global__ __launch_bounds__(512, 4) void bconv_mfma_kernel(const int8_t* __restrict__ xs,
                                                            const int8_t* __restrict__ wsB,
                                                            const float* __restrict__ bias,
                                                            float* __restrict__ out) {
    __shared__ __align__(16) int8_t Asm[2][128 * 64];   // 16 KB
    __shared__ __align__(16) int8_t Bsm[2][256 * 64];   // 32 KB

    const int m   = blockIdx.x;            // 0..783 M-tile (BN = whole N)
    const int tid = threadIdx.x;           // 0..511
    const int l   = tid & 63;
    const int wid = tid >> 6;              // 0..7
    const int lg  = l >> 4;                // k-group 0..3
    const int lr  = l & 15;                // row (A) / col (B,C)
    const int wm  = wid & 1, wn = wid >> 1;   // 2 x 4 wave grid

    const int M0 = m * 128;

    // ---- staging addresses: thread handles row tid>>2, chunk tid&3 -----------------
    const int srow0 = tid >> 2;                       // 0..127
    const int g16   = (((tid & 3) ^ ((tid >> 3) & 3)) << 4);
    uint32_t apb0, bpb0, bpb1;
    {
        int p0 = M0 + srow0;
        int n0 = p0 / SS, sp0 = p0 - n0 * SS, h0 = sp0 / WW, w0 = sp0 - h0 * WW;
        apb0 = (uint32_t)(((n0 * PH + h0) * PW + w0) * 256 + g16);
        bpb0 = (uint32_t)((srow0) * KTOT + g16);
        bpb1 = (uint32_t)((128 + srow0) * KTOT + g16);
    }

    // ---- ds_read offsets (swizzled) ------------------------------------------------
    const int swz16 = ((lg ^ ((lr >> 1) & 3)) << 4);
    int swzA[4], swzB[4];
#pragma unroll
    for (int s = 0; s < 4; ++s) swzA[s] = (wm * 64 + s * 16 + lr) * 64 + swz16;
#pragma unroll
    for (int u = 0; u < 4; ++u) swzB[u] = (wn * 64 + u * 16 + lr) * 64 + swz16;

    i32x4 acc[4][4];
#pragma unroll
    for (int s = 0; s < 4; ++s)
#pragma unroll
        for (int u = 0; u < 4; ++u)
            acc[s][u] = (i32x4){0, 0, 0, 0};

    // ---- K-loop: 36 tiles, dbuf, counted vmcnt (3 loads stay in flight) ------------
    STAGE(0, 0);
    int cur = 0;
#pragma unroll 1
    for (int kt = 0; kt < 35; ++kt) {
        STAGE(cur ^ 1, kt + 1);            // 6 outstanding
        WAITVM(3);                         // tile kt landed; kt+1 stays in flight
        __builtin_amdgcn_s_barrier();
        COMPUTE(cur);
        WAITLGKM0();
        __builtin_amdgcn_sched_barrier(0);
        __builtin_amdgcn_s_barrier();      // gates next STAGE's overwrite of cur
        cur ^= 1;
    }
    WAITVM(0);
    __builtin_amdgcn_s_barrier();
    COMPUTE(cur);

    // ---- epilogue (bit-exact mapping proven R6/R8-R12) -----------------------------
    float bo[4];
#pragma unroll
    for (int u = 0; u < 4; ++u) bo[u] = bias[wn * 64 + u * 16 + lr];

#pragma unroll
    for (int s = 0; s < 4; ++s) {
        int pst = M0 + wm * 64 + s * 16 + lg * 4;
        int n   = pst / SS;
        int sp  = pst - n * SS;
#pragma unroll
        for (int u = 0; u < 4; ++u) {
            i32x4 a = acc[s][u];
            int o = wn * 64 + u * 16 + lr;
            float v0 = (float)a.x + bo[u];
            float v1 = (float)a.y + bo[u];
            float v2 = (float)a.z + bo[u];
            float v3 = (float)a.w + bo[u];
            float4 r4;
            r4.x = (v0 > 0.f) ? 1.f : ((v0 < 0.f) ? -1.f : 0.f);
            r4.y = (v1 > 0.f) ? 1.f : ((v1 < 0.f) ? -1.f : 0.f);
            r4.z = (v2 > 0.f) ? 1.f : ((v2 < 0.f) ? -1.f : 0.f);
            r4.w = (v3 > 0.f) ? 1.f : ((v3 < 0.f) ? -1.f : 0.f);
            *(float4*)(out + ((size_t)(n * OO + o)) * SS + sp) = r4;
        }
    }
}

// ============================ fallback popcount path (R4, 163 us) ===================

#define SPAD (PH*PW)
#define CWN  4

__global__ __launch_bounds__(256) void pack_x_kernel(const float* __restrict__ x,
                                                     uint64_t* __restrict__ px) {
    int tid = threadIdx.x;
    int sp  = blockIdx.x * 256 + tid;
    int cw  = blockIdx.y;
    int n   = blockIdx.z;
    if (sp >= SPAD) return;
    int ph = sp / PW, pw_ = sp % PW;
    uint64_t* dst = px + (((size_t)n * CWN + cw) * SPAD + sp);
    if (ph == 0 || ph == PH - 1 || pw_ == 0 || pw_ == PW - 1) { *dst = 0ull; return; }
    int h = ph - 1, w = pw_ - 1;
    const float* src = x + ((size_t)(n * CC + cw * 64)) * SS + (h * WW + w);
    uint32_t lo = 0u, hi = 0u;
#pragma unroll
    for (int j = 0; j < 32; ++j) { float v = src[(size_t)j * SS];        lo |= (v > 0.0f ? 1u : 0u) << j; }
#pragma unroll
    for (int j = 0; j < 32; ++j) { float v = src[(size_t)(j + 32) * SS]; hi |= (v > 0.0f ? 1u : 0u) << j; }
    *dst = ((uint64_t)hi << 32) | (uint64_t)lo;
}

__global__ __launch_bounds__(256) void pack_w_kernel(const float* __restrict__ wgt,
                                                     uint64_t* __restrict__ pwb) {
    int lane = threadIdx.x & 63;
    int wave = threadIdx.x >> 6;
    int wi   = blockIdx.x * 4 + wave;
    if (wi >= OO * 9 * CWN) return;
    int o = wi / 36, rem = wi % 36, t = rem >> 2, cw = rem & 3;
    int c = cw * 64 + lane;
    float v = wgt[(size_t)(o * CC + c) * 9 + t];
    uint64_t m = __ballot(v > 0.0f);
    if (lane == 0) pwb[wi] = m;
}

__global__ __launch_bounds__(256) void build_k_kernel(const uint64_t* __restrict__ pwb,
                                                      int* __restrict__ ktab) {
    int o = threadIdx.x;
    int pops[9];
#pragma unroll
    for (int t = 0; t < 9; ++t) {
        int p = 0;
#pragma unroll
        for (int cw = 0; cw < 4; ++cw) p += __popcll(pwb[o * 36 + t * 4 + cw]);
        pops[t] = p;
    }
#pragma unroll
    for (int cls = 0; cls < 9; ++cls) {
        int vf = cls / 3, hf = cls % 3;
        int K = 9 * CC;
#pragma unroll
        for (int t = 0; t < 9; ++t) {
            int r = t / 3, k = t % 3;
            bool inv = (vf == 1 && r == 0) || (vf == 2 && r == 2) ||
                       (hf == 1 && k == 0) || (hf == 2 && k == 2);
            if (inv) K -= (CC - 2 * pops[t]);
        }
        ktab[cls * OO + o] = K;
    }
}

__global__ __launch_bounds__(256, 4) void bconv_kernel(const uint64_t* __restrict__ px,
                                                       const uint64_t* __restrict__ pwb,
                                                       const int* __restrict__ ktab,
                                                       const float* __restrict__ bias,
                                                       float* __restrict__ out) {
    int g = blockIdx.x * 256 + threadIdx.x;
    int n = g / SS;
    int sid = g - n * SS;
    int obase = blockIdx.y * 32;
    int h = sid / WW, w = sid - h * WW;
    int vf = (h == 0) ? 1 : ((h == HH - 1) ? 2 : 0);
    int hf = (w == 0) ? 1 : ((w == WW - 1) ? 2 : 0);
    const int* krow = ktab + (vf * 3 + hf) * OO + obase;
    const uint64_t* pb = px + (size_t)n * CWN * SPAD + h * PW + w;
    const uint32_t* wb = (const uint32_t*)pwb + (size_t)obase * 72;
    uint32_t acc[32];
#pragma unroll
    for (int i = 0; i < 32; ++i) acc[i] = 0u;
#pragma unroll 1
    for (int r = 0; r < 3; ++r) {
#pragma unroll 1
        for (int k = 0; k < 3; ++k) {
            int off = r * PW + k;
            uint64_t q0 = pb[off];
            uint64_t q1 = pb[SPAD + off];
            uint64_t q2 = pb[2 * SPAD + off];
            uint64_t q3 = pb[3 * SPAD + off];
            uint32_t pa0 = (uint32_t)q0, pa1 = (uint32_t)(q0 >> 32);
            uint32_t pa2 = (uint32_t)q1, pa3 = (uint32_t)(q1 >> 32);
            uint32_t pa4 = (uint32_t)q2, pa5 = (uint32_t)(q2 >> 32);
            uint32_t pa6 = (uint32_t)q3, pa7 = (uint32_t)(q3 >> 32);
            int t8 = (r * 3 + k) * 8;
#pragma unroll
            for (int oi = 0; oi < 32; ++oi) {
                const uint32_t* wv = wb + oi * 72 + t8;
                uint32_t a = acc[oi];
                a = __popc(pa0 ^ wv[0]) + a;
                a = __popc(pa1 ^ wv[1]) + a;
                a = __popc(pa2 ^ wv[2]) + a;
                a = __popc(pa3 ^ wv[3]) + a;
                a = __popc(pa4 ^ wv[4]) + a;
                a = __popc(pa5 ^ wv[5]) + a;
                a = __popc(pa6 ^ wv[6]) + a;
                a = __popc(pa7 ^ wv[7]) + a;
                acc[oi] = a;
            }
        }
    }
    float* orow = out + ((size_t)(n * OO + obase)) * SS + sid;
#pragma unroll
    for (int oi = 0; oi < 32; ++oi) {
        int s = krow[oi] - 2 * (int)acc[oi];
        float v = (float)s + bias[obase + oi];
        float res = (v > 0.0f) ? 1.0f : ((v < 0.0f) ? -1.0f : 0.0f);
        orow[(size_t)oi * SS] = res;
    }
}

// ============================ launch ================================================

extern "C" void kernel_launch(void* const* d_in, const int* in_sizes, int n_in,
                              void* d_out, int out_size, void* d_ws, size_t ws_size,
                              hipStream_t stream) {
    const float* x    = (const float*)d_in[0];
    const float* wgt  = (const float*)d_in[1];
    const float* bias = (const float*)d_in[2];
    float* out = (float*)d_out;

    const size_t wsB_bytes = (size_t)OO * KTOT;                 // 589,824
    const size_t xs_bytes  = (size_t)NB * PH * PW * 256;        // 27,557,888
    if (ws_size >= wsB_bytes + xs_bytes) {
        int8_t* wsB = (int8_t*)d_ws;
        int8_t* xs  = (int8_t*)d_ws + wsB_bytes;
        pack_xs_kernel<<<dim3(PH, NB), 256, 0, stream>>>(x, xs);
        pack_wsB_kernel<<<dim3(OO), 256, 0, stream>>>(wgt, wsB);
        const int n_blocks = NB * SS / 128;                     // 784 (BN = whole N)
        bconv_mfma_kernel<<<dim3(n_blocks), 512, 0, stream>>>(xs, wsB, bias, out);
    } else {
        // fallback: proven popcount path (R4)
        size_t px_bytes = (size_t)NB * CWN * SPAD * 8;
        size_t pw_off   = px_bytes;
        size_t pw_bytes = (size_t)OO * 9 * CWN * 8;
        size_t k_off    = pw_off + pw_bytes;
        uint64_t* px  = (uint64_t*)d_ws;
        uint64_t* pwb = (uint64_t*)((char*)d_ws + pw_off);
        int*      kt  = (int*)((char*)d_ws + k_off);
        dim3 gpx((SPAD + 255) / 256, CWN, NB);
        pack_x_kernel<<<gpx, 256, 0, stream>>>(x, px);
        int nwords = OO * 9 * CWN;
        pack_w_kernel<<<dim3((nwords + 3) / 4), 256, 0, stream>>>(wgt, pwb);
        build_k_kernel<<<dim3(1), 256, 0, stream>>>(pwb, kt);
        dim3 gcv(NB * SS / 256, OO / 32, 1);
        bconv_kernel<<<gcv, 256, 0, stream>>>(px, pwb, kt, bias, out);
    }
}

// Round 14
// 93.596 us; speedup vs baseline: 1.3087x; 1.2744x over previous
//
#include <hip/hip_runtime.h>
#include <stdint.h>

typedef __attribute__((ext_vector_type(4))) int   i32x4;
typedef __attribute__((ext_vector_type(8))) int   i32x8;
typedef __attribute__((ext_vector_type(4))) float f32x4;

// BinaryConv: out = sign(conv2d(sign(x), sign(w), pad=1) + bias)
// R14: MX-FP4 implicit GEMM. sign -> e2m1 nibbles (+1=0x2, -1=0xA, 0=0x0), uniform
// scale 1.0 (e8m0=0x7F) => bit-exact f32 accumulation (sums <= 2304 < 2^24).
// mfma_scale_f32_16x16x128_f8f6f4: K=128 per 16B fragment = 2x ops/LDS-byte and
// ~1.8x op rate vs i8 -- attacks the byte-per-op bound that capped R9-R13 at ~25%.
// Geometry/schedule byte-identical to R13 (verified): 64B LDS rows, same swizzle,
// same staging chunks, same counted-vmcnt dbuf loop, same 16x16 C/D epilogue.

#define NB 32
#define CC 256
#define HH 56
#define WW 56
#define OO 256
#define PH 58
#define PW 58
#define SS (HH*WW)      // 3136
#define KTOT 2304
#define BROW4 1152      // wsB4 row bytes: 9 taps x 128 ch-pairs
#define PIX4  128       // xs4 bytes per pixel

// ---- async global->LDS, 16B per lane; dest = wave-uniform base + lane*16 -----------
__device__ __forceinline__ void gload16(const void* g, void* l) {
    const __attribute__((address_space(1))) void* gp =
        reinterpret_cast<const __attribute__((address_space(1))) void*>(
            reinterpret_cast<uintptr_t>(g));
    __attribute__((address_space(3))) void* lp =
        reinterpret_cast<__attribute__((address_space(3))) void*>(
            static_cast<uintptr_t>(static_cast<uint32_t>(reinterpret_cast<uintptr_t>(l))));
    __builtin_amdgcn_global_load_lds(gp, lp, 16, 0, 0);
}

#define WAITVM(N) asm volatile("s_waitcnt vmcnt(" #N ")" ::: "memory")
#define WAITLGKM0() asm volatile("s_waitcnt lgkmcnt(0)" ::: "memory")

__device__ __forceinline__ uint8_t nib4(float v) {
    return (v > 0.f) ? 0x2u : ((v < 0.f) ? 0xAu : 0x0u);   // e2m1 +1 / -1 / 0
}

// ============================ pack kernels ==========================================

// xs4: [n][ph][pw][c/2] fp4-pair bytes, border pixels = 0. Thread j = channel pair.
__global__ __launch_bounds__(128) void pack_xs4_kernel(const float* __restrict__ x,
                                                       uint8_t* __restrict__ xs4) {
    int j  = threadIdx.x;          // 0..127 channel pair
    int ph = blockIdx.x;
    int n  = blockIdx.y;
    uint8_t* dst = xs4 + (((size_t)n * PH + ph) * PW) * PIX4 + j;
    if (ph == 0 || ph == PH - 1) {
        for (int pw = 0; pw < PW; ++pw) dst[(size_t)pw * PIX4] = 0;
        return;
    }
    int h = ph - 1;
    const float4* s0 = (const float4*)(x + ((size_t)(n * CC + 2 * j) * HH + h) * WW);
    const float4* s1 = (const float4*)(x + ((size_t)(n * CC + 2 * j + 1) * HH + h) * WW);
    float4 r0[14], r1[14];
#pragma unroll
    for (int i = 0; i < 14; ++i) { r0[i] = s0[i]; r1[i] = s1[i]; }
    dst[0] = 0;
    dst[(size_t)(PW - 1) * PIX4] = 0;
    const float* a = (const float*)r0;
    const float* b = (const float*)r1;
#pragma unroll
    for (int w = 0; w < 56; ++w)
        dst[(size_t)(w + 1) * PIX4] = (uint8_t)(nib4(a[w]) | (nib4(b[w]) << 4));
}

// wsB4: [o][t][c/2] fp4-pair bytes (row = 1152 B)
__global__ __launch_bounds__(128) void pack_wsB4_kernel(const float* __restrict__ wgt,
                                                        uint8_t* __restrict__ wsB4) {
    int j = threadIdx.x;           // channel pair
    int o = blockIdx.x;
    const float* s0 = wgt + ((size_t)o * CC + 2 * j) * 9;
    const float* s1 = wgt + ((size_t)o * CC + 2 * j + 1) * 9;
#pragma unroll
    for (int t = 0; t < 9; ++t)
        wsB4[(size_t)o * BROW4 + t * 128 + j] = (uint8_t)(nib4(s0[t]) | (nib4(s1[t]) << 4));
}

// ============================ MFMA GEMM (MX-FP4) ====================================
// Block = 8 waves (2M x 4N), 512 threads. Tile 128 px x 256 ch, K-tile = 128 elems
// (64 B/row). 18 K-tiles. LDS: A[2][128*64]=16KB + B[2][256*64]=32KB = 48KB dbuf;
// STAGE = 3 gload16/thread. Counted vmcnt(3) keeps next tile's loads in flight.
// Swizzle identical to R9-R13 (bit-exact): LDS[row][chunk]=GLOBAL[row][chunk^((row>>1)&3)].

#define STAGE(BUF, KT) do {                                                  \
    const int _t = (KT) >> 1, _q = (KT) & 1;                                 \
    const uint32_t _at = (uint32_t)(((_t / 3) * PW + (_t % 3)) * PIX4 + _q * 64); \
    const uint32_t _bt = (uint32_t)(_t * 128 + _q * 64);                     \
    gload16(xs4 + (apb0 + _at), &Asm[BUF][wid * 1024]);                      \
    gload16(wsB4 + (bpb0 + _bt), &Bsm[BUF][wid * 1024]);                     \
    gload16(wsB4 + (bpb1 + _bt), &Bsm[BUF][8192 + wid * 1024]);              \
} while (0)

#define COMPUTE(BUF) do {                                                    \
    const uint8_t* _Ab = &Asm[BUF][0];                                       \
    const uint8_t* _Bb = &Bsm[BUF][0];                                       \
    i32x4 af[4], bf[4];                                                      \
    _Pragma("unroll")                                                        \
    for (int _s = 0; _s < 4; ++_s) af[_s] = *(const i32x4*)(_Ab + swzA[_s]); \
    _Pragma("unroll")                                                        \
    for (int _u = 0; _u < 4; ++_u) bf[_u] = *(const i32x4*)(_Bb + swzB[_u]); \
    WAITLGKM0();                                                             \
    __builtin_amdgcn_sched_barrier(0);                                      \
    _Pragma("unroll")                                                        \
    for (int _s = 0; _s < 4; ++_s) {                                         \
        i32x8 _a8 = (i32x8){af[_s].x, af[_s].y, af[_s].z, af[_s].w, 0, 0, 0, 0}; \
        _Pragma("unroll")                                                    \
        for (int _u = 0; _u < 4; ++_u) {                                     \
            i32x8 _b8 = (i32x8){bf[_u].x, bf[_u].y, bf[_u].z, bf[_u].w, 0, 0, 0, 0}; \
            acc[_s][_u] = __builtin_amdgcn_mfma_scale_f32_16x16x128_f8f6f4(  \
                _a8, _b8, acc[_s][_u], 4, 4, 0, 0x7F7F7F7F, 0, 0x7F7F7F7F);  \
        }                                                                    \
    }                                                                        \
} while (0)

__global__ __launch_bounds__(512, 3) void bconv_mfma_kernel(const uint8_t* __restrict__ xs4,
                                                            const uint8_t* __restrict__ wsB4,
                                                            const float* __restrict__ bias,
                                                            float* __restrict__ out) {
    __shared__ __align__(16) uint8_t Asm[2][128 * 64];   // 8 KB each
    __shared__ __align__(16) uint8_t Bsm[2][256 * 64];   // 16 KB each

    const int m   = blockIdx.x;            // 0..783 M-tile (BN = whole N)
    const int tid = threadIdx.x;           // 0..511
    const int l   = tid & 63;
    const int wid = tid >> 6;              // 0..7
    const int lg  = l >> 4;                // k-group 0..3 (32 fp4 elems each)
    const int lr  = l & 15;                // row (A) / col (B,C)
    const int wm  = wid & 1, wn = wid >> 1;   // 2 x 4 wave grid

    const int M0 = m * 128;

    // ---- staging addresses: thread handles row tid>>2, chunk tid&3 -----------------
    const int srow0 = tid >> 2;                       // 0..127
    const int g16   = (((tid & 3) ^ ((tid >> 3) & 3)) << 4);
    uint32_t apb0, bpb0, bpb1;
    {
        int p0 = M0 + srow0;
        int n0 = p0 / SS, sp0 = p0 - n0 * SS, h0 = sp0 / WW, w0 = sp0 - h0 * WW;
        apb0 = (uint32_t)(((n0 * PH + h0) * PW + w0) * PIX4 + g16);
        bpb0 = (uint32_t)((srow0) * BROW4 + g16);
        bpb1 = (uint32_t)((128 + srow0) * BROW4 + g16);
    }

    // ---- ds_read offsets (swizzled) ------------------------------------------------
    const int swz16 = ((lg ^ ((lr >> 1) & 3)) << 4);
    int swzA[4], swzB[4];
#pragma unroll
    for (int s = 0; s < 4; ++s) swzA[s] = (wm * 64 + s * 16 + lr) * 64 + swz16;
#pragma unroll
    for (int u = 0; u < 4; ++u) swzB[u] = (wn * 64 + u * 16 + lr) * 64 + swz16;

    f32x4 acc[4][4];
#pragma unroll
    for (int s = 0; s < 4; ++s)
#pragma unroll
        for (int u = 0; u < 4; ++u)
            acc[s][u] = (f32x4){0.f, 0.f, 0.f, 0.f};

    // ---- K-loop: 18 tiles of K=128, dbuf, counted vmcnt ----------------------------
    STAGE(0, 0);
    int cur = 0;
#pragma unroll 1
    for (int kt = 0; kt < 17; ++kt) {
        STAGE(cur ^ 1, kt + 1);            // 6 outstanding
        WAITVM(3);                         // tile kt landed; kt+1 stays in flight
        __builtin_amdgcn_s_barrier();
        COMPUTE(cur);
        WAITLGKM0();
        __builtin_amdgcn_sched_barrier(0);
        __builtin_amdgcn_s_barrier();      // gates next STAGE's overwrite of cur
        cur ^= 1;
    }
    WAITVM(0);
    __builtin_amdgcn_s_barrier();
    COMPUTE(cur);

    // ---- epilogue: C/D col=lr, row=lg*4+reg (verified, shape-determined) -----------
    float bo[4];
#pragma unroll
    for (int u = 0; u < 4; ++u) bo[u] = bias[wn * 64 + u * 16 + lr];

#pragma unroll
    for (int s = 0; s < 4; ++s) {
        int pst = M0 + wm * 64 + s * 16 + lg * 4;
        int n   = pst / SS;
        int sp  = pst - n * SS;
#pragma unroll
        for (int u = 0; u < 4; ++u) {
            f32x4 a = acc[s][u];
            int o = wn * 64 + u * 16 + lr;
            float v0 = a.x + bo[u];
            float v1 = a.y + bo[u];
            float v2 = a.z + bo[u];
            float v3 = a.w + bo[u];
            float4 r4;
            r4.x = (v0 > 0.f) ? 1.f : ((v0 < 0.f) ? -1.f : 0.f);
            r4.y = (v1 > 0.f) ? 1.f : ((v1 < 0.f) ? -1.f : 0.f);
            r4.z = (v2 > 0.f) ? 1.f : ((v2 < 0.f) ? -1.f : 0.f);
            r4.w = (v3 > 0.f) ? 1.f : ((v3 < 0.f) ? -1.f : 0.f);
            *(float4*)(out + ((size_t)(n * OO + o)) * SS + sp) = r4;
        }
    }
}

// ============================ fallback popcount path (R4, 163 us) ===================

#define SPAD (PH*PW)
#define CWN  4

__global__ __launch_bounds__(256) void pack_x_kernel(const float* __restrict__ x,
                                                     uint64_t* __restrict__ px) {
    int tid = threadIdx.x;
    int sp  = blockIdx.x * 256 + tid;
    int cw  = blockIdx.y;
    int n   = blockIdx.z;
    if (sp >= SPAD) return;
    int ph = sp / PW, pw_ = sp % PW;
    uint64_t* dst = px + (((size_t)n * CWN + cw) * SPAD + sp);
    if (ph == 0 || ph == PH - 1 || pw_ == 0 || pw_ == PW - 1) { *dst = 0ull; return; }
    int h = ph - 1, w = pw_ - 1;
    const float* src = x + ((size_t)(n * CC + cw * 64)) * SS + (h * WW + w);
    uint32_t lo = 0u, hi = 0u;
#pragma unroll
    for (int j = 0; j < 32; ++j) { float v = src[(size_t)j * SS];        lo |= (v > 0.0f ? 1u : 0u) << j; }
#pragma unroll
    for (int j = 0; j < 32; ++j) { float v = src[(size_t)(j + 32) * SS]; hi |= (v > 0.0f ? 1u : 0u) << j; }
    *dst = ((uint64_t)hi << 32) | (uint64_t)lo;
}

__global__ __launch_bounds__(256) void pack_w_kernel(const float* __restrict__ wgt,
                                                     uint64_t* __restrict__ pwb) {
    int lane = threadIdx.x & 63;
    int wave = threadIdx.x >> 6;
    int wi   = blockIdx.x * 4 + wave;
    if (wi >= OO * 9 * CWN) return;
    int o = wi / 36, rem = wi % 36, t = rem >> 2, cw = rem & 3;
    int c = cw * 64 + lane;
    float v = wgt[(size_t)(o * CC + c) * 9 + t];
    uint64_t m = __ballot(v > 0.0f);
    if (lane == 0) pwb[wi] = m;
}

__global__ __launch_bounds__(256) void build_k_kernel(const uint64_t* __restrict__ pwb,
                                                      int* __restrict__ ktab) {
    int o = threadIdx.x;
    int pops[9];
#pragma unroll
    for (int t = 0; t < 9; ++t) {
        int p = 0;
#pragma unroll
        for (int cw = 0; cw < 4; ++cw) p += __popcll(pwb[o * 36 + t * 4 + cw]);
        pops[t] = p;
    }
#pragma unroll
    for (int cls = 0; cls < 9; ++cls) {
        int vf = cls / 3, hf = cls % 3;
        int K = 9 * CC;
#pragma unroll
        for (int t = 0; t < 9; ++t) {
            int r = t / 3, k = t % 3;
            bool inv = (vf == 1 && r == 0) || (vf == 2 && r == 2) ||
                       (hf == 1 && k == 0) || (hf == 2 && k == 2);
            if (inv) K -= (CC - 2 * pops[t]);
        }
        ktab[cls * OO + o] = K;
    }
}

__global__ __launch_bounds__(256, 4) void bconv_kernel(const uint64_t* __restrict__ px,
                                                       const uint64_t* __restrict__ pwb,
                                                       const int* __restrict__ ktab,
                                                       const float* __restrict__ bias,
                                                       float* __restrict__ out) {
    int g = blockIdx.x * 256 + threadIdx.x;
    int n = g / SS;
    int sid = g - n * SS;
    int obase = blockIdx.y * 32;
    int h = sid / WW, w = sid - h * WW;
    int vf = (h == 0) ? 1 : ((h == HH - 1) ? 2 : 0);
    int hf = (w == 0) ? 1 : ((w == WW - 1) ? 2 : 0);
    const int* krow = ktab + (vf * 3 + hf) * OO + obase;
    const uint64_t* pb = px + (size_t)n * CWN * SPAD + h * PW + w;
    const uint32_t* wb = (const uint32_t*)pwb + (size_t)obase * 72;
    uint32_t acc[32];
#pragma unroll
    for (int i = 0; i < 32; ++i) acc[i] = 0u;
#pragma unroll 1
    for (int r = 0; r < 3; ++r) {
#pragma unroll 1
        for (int k = 0; k < 3; ++k) {
            int off = r * PW + k;
            uint64_t q0 = pb[off];
            uint64_t q1 = pb[SPAD + off];
            uint64_t q2 = pb[2 * SPAD + off];
            uint64_t q3 = pb[3 * SPAD + off];
            uint32_t pa0 = (uint32_t)q0, pa1 = (uint32_t)(q0 >> 32);
            uint32_t pa2 = (uint32_t)q1, pa3 = (uint32_t)(q1 >> 32);
            uint32_t pa4 = (uint32_t)q2, pa5 = (uint32_t)(q2 >> 32);
            uint32_t pa6 = (uint32_t)q3, pa7 = (uint32_t)(q3 >> 32);
            int t8 = (r * 3 + k) * 8;
#pragma unroll
            for (int oi = 0; oi < 32; ++oi) {
                const uint32_t* wv = wb + oi * 72 + t8;
                uint32_t a = acc[oi];
                a = __popc(pa0 ^ wv[0]) + a;
                a = __popc(pa1 ^ wv[1]) + a;
                a = __popc(pa2 ^ wv[2]) + a;
                a = __popc(pa3 ^ wv[3]) + a;
                a = __popc(pa4 ^ wv[4]) + a;
                a = __popc(pa5 ^ wv[5]) + a;
                a = __popc(pa6 ^ wv[6]) + a;
                a = __popc(pa7 ^ wv[7]) + a;
                acc[oi] = a;
            }
        }
    }
    float* orow = out + ((size_t)(n * OO + obase)) * SS + sid;
#pragma unroll
    for (int oi = 0; oi < 32; ++oi) {
        int s = krow[oi] - 2 * (int)acc[oi];
        float v = (float)s + bias[obase + oi];
        float res = (v > 0.0f) ? 1.0f : ((v < 0.0f) ? -1.0f : 0.0f);
        orow[(size_t)oi * SS] = res;
    }
}

// ============================ launch ================================================

extern "C" void kernel_launch(void* const* d_in, const int* in_sizes, int n_in,
                              void* d_out, int out_size, void* d_ws, size_t ws_size,
                              hipStream_t stream) {
    const float* x    = (const float*)d_in[0];
    const float* wgt  = (const float*)d_in[1];
    const float* bias = (const float*)d_in[2];
    float* out = (float*)d_out;

    const size_t wsB4_bytes = (size_t)OO * BROW4;               // 294,912
    const size_t xs4_bytes  = (size_t)NB * PH * PW * PIX4;      // 13,778,944
    if (ws_size >= wsB4_bytes + xs4_bytes) {
        uint8_t* wsB4 = (uint8_t*)d_ws;
        uint8_t* xs4  = (uint8_t*)d_ws + wsB4_bytes;
        pack_xs4_kernel<<<dim3(PH, NB), 128, 0, stream>>>(x, xs4);
        pack_wsB4_kernel<<<dim3(OO), 128, 0, stream>>>(wgt, wsB4);
        const int n_blocks = NB * SS / 128;                     // 784 (BN = whole N)
        bconv_mfma_kernel<<<dim3(n_blocks), 512, 0, stream>>>(xs4, wsB4, bias, out);
    } else {
        // fallback: proven popcount path (R4)
        size_t px_bytes = (size_t)NB * CWN * SPAD * 8;
        size_t pw_off   = px_bytes;
        size_t pw_bytes = (size_t)OO * 9 * CWN * 8;
        size_t k_off    = pw_off + pw_bytes;
        uint64_t* px  = (uint64_t*)d_ws;
        uint64_t* pwb = (uint64_t*)((char*)d_ws + pw_off);
        int*      kt  = (int*)((char*)d_ws + k_off);
        dim3 gpx((SPAD + 255) / 256, CWN, NB);
        pack_x_kernel<<<gpx, 256, 0, stream>>>(x, px);
        int nwords = OO * 9 * CWN;
        pack_w_kernel<<<dim3((nwords + 3) / 4), 256, 0, stream>>>(wgt, pwb);
        build_k_kernel<<<dim3(1), 256, 0, stream>>>(pwb, kt);
        dim3 gcv(NB * SS / 256, OO / 32, 1);
        bconv_kernel<<<gcv, 256, 0, stream>>>(px, pwb, kt, bias, out);
    }
}

// Round 15
// 81.548 us; speedup vs baseline: 1.5020x; 1.1477x over previous
//
#include <hip/hip_runtime.h>
#include <stdint.h>

typedef __attribute__((ext_vector_type(4))) int   i32x4;
typedef __attribute__((ext_vector_type(8))) int   i32x8;
typedef __attribute__((ext_vector_type(4))) float f32x4;

// BinaryConv: out = sign(conv2d(sign(x), sign(w), pad=1) + bias)
// R15: MX-FP4 implicit GEMM (R14, verified bit-exact, ~30us) + rewritten pack_xs4:
// coalesced global reads + LDS transpose (pitch-65 rows), in-kernel border zeroing.
// R14's pack was transaction-rate-bound (2.1 TB/s, 64 cache lines per wave load).

#define NB 32
#define CC 256
#define HH 56
#define WW 56
#define OO 256
#define PH 58
#define PW 58
#define SS (HH*WW)      // 3136
#define KTOT 2304
#define BROW4 1152      // wsB4 row bytes: 9 taps x 128 ch-pairs
#define PIX4  128       // xs4 bytes per pixel

// ---- async global->LDS, 16B per lane; dest = wave-uniform base + lane*16 -----------
__device__ __forceinline__ void gload16(const void* g, void* l) {
    const __attribute__((address_space(1))) void* gp =
        reinterpret_cast<const __attribute__((address_space(1))) void*>(
            reinterpret_cast<uintptr_t>(g));
    __attribute__((address_space(3))) void* lp =
        reinterpret_cast<__attribute__((address_space(3))) void*>(
            static_cast<uintptr_t>(static_cast<uint32_t>(reinterpret_cast<uintptr_t>(l))));
    __builtin_amdgcn_global_load_lds(gp, lp, 16, 0, 0);
}

#define WAITVM(N) asm volatile("s_waitcnt vmcnt(" #N ")" ::: "memory")
#define WAITLGKM0() asm volatile("s_waitcnt lgkmcnt(0)" ::: "memory")

__device__ __forceinline__ uint8_t nib4(float v) {
    return (v > 0.f) ? 0x2u : ((v < 0.f) ? 0xAu : 0x0u);   // e2m1 +1 / -1 / 0
}

// ============================ pack kernels ==========================================

// xs4: [n][ph][pw][c/2] fp4-pair bytes, border pixels = 0.
// Block = (h, n), 256 threads. Phase 1: flat float4 sweep over the [c][w] slab ->
// runs of 14 lanes read contiguous 224B segments (coalesced); nibbles staged in LDS
// [c][w] pitch 65. Phase 2: coalesced u32 writes of pair-bytes; borders zeroed here.
__global__ __launch_bounds__(256) void pack_xs4_kernel(const float* __restrict__ x,
                                                       uint8_t* __restrict__ xs4) {
    __shared__ uint8_t lt[256 * 65];      // 16640 B
    const int t = threadIdx.x;
    const int h = blockIdx.x;             // 0..55
    const int n = blockIdx.y;
    const float* xbase = x + (size_t)n * CC * SS + h * WW;

#pragma unroll
    for (int i = 0; i < 14; ++i) {
        int f = i * 256 + t;              // 0..3583 flat float4 index
        int c = f / 14;                   // channel
        int q = f - c * 14;               // float4-quad within the 56-float row
        const float4 v = *(const float4*)(xbase + (size_t)c * SS + q * 4);
        uint8_t* lrow = &lt[c * 65 + 4 * q];
        lrow[0] = nib4(v.x);
        lrow[1] = nib4(v.y);
        lrow[2] = nib4(v.z);
        lrow[3] = nib4(v.w);
    }
    __syncthreads();

    uint8_t* orow = xs4 + (((size_t)n * PH + (h + 1)) * PW) * PIX4;
    uint32_t* orow32 = (uint32_t*)orow;

    // interior pixels pw=1..56: 56 x 32 u32
    for (int ot = t; ot < 56 * 32; ot += 256) {
        int pwl = ot >> 5;                // pixel 0..55
        int k4  = ot & 31;                // u32 within pixel (8 channels)
        uint32_t r = 0;
#pragma unroll
        for (int b = 0; b < 4; ++b) {
            uint32_t lo = lt[(8 * k4 + 2 * b)     * 65 + pwl];
            uint32_t hi = lt[(8 * k4 + 2 * b + 1) * 65 + pwl];
            r |= ((lo | (hi << 4)) & 0xFFu) << (8 * b);
        }
        orow32[(pwl + 1) * 32 + k4] = r;
    }
    // border pixels pw=0 and pw=57 of this row
    if (t < 64) {
        int pix = (t < 32) ? 0 : (PW - 1);
        orow32[pix * 32 + (t & 31)] = 0u;
    }
    // border rows ph=0 (h==0) and ph=57 (h==55)
    if (h == 0) {
        uint32_t* z = (uint32_t*)(xs4 + ((size_t)n * PH * PW) * PIX4);
        for (int i = t; i < PW * 32; i += 256) z[i] = 0u;
    }
    if (h == HH - 1) {
        uint32_t* z = (uint32_t*)(xs4 + (((size_t)n * PH + (PH - 1)) * PW) * PIX4);
        for (int i = t; i < PW * 32; i += 256) z[i] = 0u;
    }
}

// wsB4: [o][t][c/2] fp4-pair bytes (row = 1152 B)
__global__ __launch_bounds__(128) void pack_wsB4_kernel(const float* __restrict__ wgt,
                                                        uint8_t* __restrict__ wsB4) {
    int j = threadIdx.x;           // channel pair
    int o = blockIdx.x;
    const float* s0 = wgt + ((size_t)o * CC + 2 * j) * 9;
    const float* s1 = wgt + ((size_t)o * CC + 2 * j + 1) * 9;
#pragma unroll
    for (int t = 0; t < 9; ++t)
        wsB4[(size_t)o * BROW4 + t * 128 + j] = (uint8_t)(nib4(s0[t]) | (nib4(s1[t]) << 4));
}

// ============================ MFMA GEMM (MX-FP4, verified R14) ======================
// Block = 8 waves (2M x 4N), 512 threads. Tile 128 px x 256 ch, K-tile = 128 elems
// (64 B/row). 18 K-tiles. LDS: A[2][128*64]=16KB + B[2][256*64]=32KB dbuf;
// STAGE = 3 gload16/thread. Counted vmcnt(3). Swizzle bit-exact since R9.

#define STAGE(BUF, KT) do {                                                  \
    const int _t = (KT) >> 1, _q = (KT) & 1;                                 \
    const uint32_t _at = (uint32_t)(((_t / 3) * PW + (_t % 3)) * PIX4 + _q * 64); \
    const uint32_t _bt = (uint32_t)(_t * 128 + _q * 64);                     \
    gload16(xs4 + (apb0 + _at), &Asm[BUF][wid * 1024]);                      \
    gload16(wsB4 + (bpb0 + _bt), &Bsm[BUF][wid * 1024]);                     \
    gload16(wsB4 + (bpb1 + _bt), &Bsm[BUF][8192 + wid * 1024]);              \
} while (0)

#define COMPUTE(BUF) do {                                                    \
    const uint8_t* _Ab = &Asm[BUF][0];                                       \
    const uint8_t* _Bb = &Bsm[BUF][0];                                       \
    i32x4 af[4], bf[4];                                                      \
    _Pragma("unroll")                                                        \
    for (int _s = 0; _s < 4; ++_s) af[_s] = *(const i32x4*)(_Ab + swzA[_s]); \
    _Pragma("unroll")                                                        \
    for (int _u = 0; _u < 4; ++_u) bf[_u] = *(const i32x4*)(_Bb + swzB[_u]); \
    WAITLGKM0();                                                             \
    __builtin_amdgcn_sched_barrier(0);                                      \
    _Pragma("unroll")                                                        \
    for (int _s = 0; _s < 4; ++_s) {                                         \
        i32x8 _a8 = (i32x8){af[_s].x, af[_s].y, af[_s].z, af[_s].w, 0, 0, 0, 0}; \
        _Pragma("unroll")                                                    \
        for (int _u = 0; _u < 4; ++_u) {                                     \
            i32x8 _b8 = (i32x8){bf[_u].x, bf[_u].y, bf[_u].z, bf[_u].w, 0, 0, 0, 0}; \
            acc[_s][_u] = __builtin_amdgcn_mfma_scale_f32_16x16x128_f8f6f4(  \
                _a8, _b8, acc[_s][_u], 4, 4, 0, 0x7F7F7F7F, 0, 0x7F7F7F7F);  \
        }                                                                    \
    }                                                                        \
} while (0)

__global__ __launch_bounds__(512, 3) void bconv_mfma_kernel(const uint8_t* __restrict__ xs4,
                                                            const uint8_t* __restrict__ wsB4,
                                                            const float* __restrict__ bias,
                                                            float* __restrict__ out) {
    __shared__ __align__(16) uint8_t Asm[2][128 * 64];   // 8 KB each
    __shared__ __align__(16) uint8_t Bsm[2][256 * 64];   // 16 KB each

    const int m   = blockIdx.x;            // 0..783 M-tile (BN = whole N)
    const int tid = threadIdx.x;           // 0..511
    const int l   = tid & 63;
    const int wid = tid >> 6;              // 0..7
    const int lg  = l >> 4;                // k-group 0..3 (32 fp4 elems each)
    const int lr  = l & 15;                // row (A) / col (B,C)
    const int wm  = wid & 1, wn = wid >> 1;   // 2 x 4 wave grid

    const int M0 = m * 128;

    // ---- staging addresses: thread handles row tid>>2, chunk tid&3 -----------------
    const int srow0 = tid >> 2;                       // 0..127
    const int g16   = (((tid & 3) ^ ((tid >> 3) & 3)) << 4);
    uint32_t apb0, bpb0, bpb1;
    {
        int p0 = M0 + srow0;
        int n0 = p0 / SS, sp0 = p0 - n0 * SS, h0 = sp0 / WW, w0 = sp0 - h0 * WW;
        apb0 = (uint32_t)(((n0 * PH + h0) * PW + w0) * PIX4 + g16);
        bpb0 = (uint32_t)((srow0) * BROW4 + g16);
        bpb1 = (uint32_t)((128 + srow0) * BROW4 + g16);
    }

    // ---- ds_read offsets (swizzled) ------------------------------------------------
    const int swz16 = ((lg ^ ((lr >> 1) & 3)) << 4);
    int swzA[4], swzB[4];
#pragma unroll
    for (int s = 0; s < 4; ++s) swzA[s] = (wm * 64 + s * 16 + lr) * 64 + swz16;
#pragma unroll
    for (int u = 0; u < 4; ++u) swzB[u] = (wn * 64 + u * 16 + lr) * 64 + swz16;

    f32x4 acc[4][4];
#pragma unroll
    for (int s = 0; s < 4; ++s)
#pragma unroll
        for (int u = 0; u < 4; ++u)
            acc[s][u] = (f32x4){0.f, 0.f, 0.f, 0.f};

    // ---- K-loop: 18 tiles of K=128, dbuf, counted vmcnt ----------------------------
    STAGE(0, 0);
    int cur = 0;
#pragma unroll 1
    for (int kt = 0; kt < 17; ++kt) {
        STAGE(cur ^ 1, kt + 1);            // 6 outstanding
        WAITVM(3);                         // tile kt landed; kt+1 stays in flight
        __builtin_amdgcn_s_barrier();
        COMPUTE(cur);
        WAITLGKM0();
        __builtin_amdgcn_sched_barrier(0);
        __builtin_amdgcn_s_barrier();      // gates next STAGE's overwrite of cur
        cur ^= 1;
    }
    WAITVM(0);
    __builtin_amdgcn_s_barrier();
    COMPUTE(cur);

    // ---- epilogue: C/D col=lr, row=lg*4+reg (verified, shape-determined) -----------
    float bo[4];
#pragma unroll
    for (int u = 0; u < 4; ++u) bo[u] = bias[wn * 64 + u * 16 + lr];

#pragma unroll
    for (int s = 0; s < 4; ++s) {
        int pst = M0 + wm * 64 + s * 16 + lg * 4;
        int n   = pst / SS;
        int sp  = pst - n * SS;
#pragma unroll
        for (int u = 0; u < 4; ++u) {
            f32x4 a = acc[s][u];
            int o = wn * 64 + u * 16 + lr;
            float v0 = a.x + bo[u];
            float v1 = a.y + bo[u];
            float v2 = a.z + bo[u];
            float v3 = a.w + bo[u];
            float4 r4;
            r4.x = (v0 > 0.f) ? 1.f : ((v0 < 0.f) ? -1.f : 0.f);
            r4.y = (v1 > 0.f) ? 1.f : ((v1 < 0.f) ? -1.f : 0.f);
            r4.z = (v2 > 0.f) ? 1.f : ((v2 < 0.f) ? -1.f : 0.f);
            r4.w = (v3 > 0.f) ? 1.f : ((v3 < 0.f) ? -1.f : 0.f);
            *(float4*)(out + ((size_t)(n * OO + o)) * SS + sp) = r4;
        }
    }
}

// ============================ fallback popcount path (R4, 163 us) ===================

#define SPAD (PH*PW)
#define CWN  4

__global__ __launch_bounds__(256) void pack_x_kernel(const float* __restrict__ x,
                                                     uint64_t* __restrict__ px) {
    int tid = threadIdx.x;
    int sp  = blockIdx.x * 256 + tid;
    int cw  = blockIdx.y;
    int n   = blockIdx.z;
    if (sp >= SPAD) return;
    int ph = sp / PW, pw_ = sp % PW;
    uint64_t* dst = px + (((size_t)n * CWN + cw) * SPAD + sp);
    if (ph == 0 || ph == PH - 1 || pw_ == 0 || pw_ == PW - 1) { *dst = 0ull; return; }
    int h = ph - 1, w = pw_ - 1;
    const float* src = x + ((size_t)(n * CC + cw * 64)) * SS + (h * WW + w);
    uint32_t lo = 0u, hi = 0u;
#pragma unroll
    for (int j = 0; j < 32; ++j) { float v = src[(size_t)j * SS];        lo |= (v > 0.0f ? 1u : 0u) << j; }
#pragma unroll
    for (int j = 0; j < 32; ++j) { float v = src[(size_t)(j + 32) * SS]; hi |= (v > 0.0f ? 1u : 0u) << j; }
    *dst = ((uint64_t)hi << 32) | (uint64_t)lo;
}

__global__ __launch_bounds__(256) void pack_w_kernel(const float* __restrict__ wgt,
                                                     uint64_t* __restrict__ pwb) {
    int lane = threadIdx.x & 63;
    int wave = threadIdx.x >> 6;
    int wi   = blockIdx.x * 4 + wave;
    if (wi >= OO * 9 * CWN) return;
    int o = wi / 36, rem = wi % 36, t = rem >> 2, cw = rem & 3;
    int c = cw * 64 + lane;
    float v = wgt[(size_t)(o * CC + c) * 9 + t];
    uint64_t m = __ballot(v > 0.0f);
    if (lane == 0) pwb[wi] = m;
}

__global__ __launch_bounds__(256) void build_k_kernel(const uint64_t* __restrict__ pwb,
                                                      int* __restrict__ ktab) {
    int o = threadIdx.x;
    int pops[9];
#pragma unroll
    for (int t = 0; t < 9; ++t) {
        int p = 0;
#pragma unroll
        for (int cw = 0; cw < 4; ++cw) p += __popcll(pwb[o * 36 + t * 4 + cw]);
        pops[t] = p;
    }
#pragma unroll
    for (int cls = 0; cls < 9; ++cls) {
        int vf = cls / 3, hf = cls % 3;
        int K = 9 * CC;
#pragma unroll
        for (int t = 0; t < 9; ++t) {
            int r = t / 3, k = t % 3;
            bool inv = (vf == 1 && r == 0) || (vf == 2 && r == 2) ||
                       (hf == 1 && k == 0) || (hf == 2 && k == 2);
            if (inv) K -= (CC - 2 * pops[t]);
        }
        ktab[cls * OO + o] = K;
    }
}

__global__ __launch_bounds__(256, 4) void bconv_kernel(const uint64_t* __restrict__ px,
                                                       const uint64_t* __restrict__ pwb,
                                                       const int* __restrict__ ktab,
                                                       const float* __restrict__ bias,
                                                       float* __restrict__ out) {
    int g = blockIdx.x * 256 + threadIdx.x;
    int n = g / SS;
    int sid = g - n * SS;
    int obase = blockIdx.y * 32;
    int h = sid / WW, w = sid - h * WW;
    int vf = (h == 0) ? 1 : ((h == HH - 1) ? 2 : 0);
    int hf = (w == 0) ? 1 : ((w == WW - 1) ? 2 : 0);
    const int* krow = ktab + (vf * 3 + hf) * OO + obase;
    const uint64_t* pb = px + (size_t)n * CWN * SPAD + h * PW + w;
    const uint32_t* wb = (const uint32_t*)pwb + (size_t)obase * 72;
    uint32_t acc[32];
#pragma unroll
    for (int i = 0; i < 32; ++i) acc[i] = 0u;
#pragma unroll 1
    for (int r = 0; r < 3; ++r) {
#pragma unroll 1
        for (int k = 0; k < 3; ++k) {
            int off = r * PW + k;
            uint64_t q0 = pb[off];
            uint64_t q1 = pb[SPAD + off];
            uint64_t q2 = pb[2 * SPAD + off];
            uint64_t q3 = pb[3 * SPAD + off];
            uint32_t pa0 = (uint32_t)q0, pa1 = (uint32_t)(q0 >> 32);
            uint32_t pa2 = (uint32_t)q1, pa3 = (uint32_t)(q1 >> 32);
            uint32_t pa4 = (uint32_t)q2, pa5 = (uint32_t)(q2 >> 32);
            uint32_t pa6 = (uint32_t)q3, pa7 = (uint32_t)(q3 >> 32);
            int t8 = (r * 3 + k) * 8;
#pragma unroll
            for (int oi = 0; oi < 32; ++oi) {
                const uint32_t* wv = wb + oi * 72 + t8;
                uint32_t a = acc[oi];
                a = __popc(pa0 ^ wv[0]) + a;
                a = __popc(pa1 ^ wv[1]) + a;
                a = __popc(pa2 ^ wv[2]) + a;
                a = __popc(pa3 ^ wv[3]) + a;
                a = __popc(pa4 ^ wv[4]) + a;
                a = __popc(pa5 ^ wv[5]) + a;
                a = __popc(pa6 ^ wv[6]) + a;
                a = __popc(pa7 ^ wv[7]) + a;
                acc[oi] = a;
            }
        }
    }
    float* orow = out + ((size_t)(n * OO + obase)) * SS + sid;
#pragma unroll
    for (int oi = 0; oi < 32; ++oi) {
        int s = krow[oi] - 2 * (int)acc[oi];
        float v = (float)s + bias[obase + oi];
        float res = (v > 0.0f) ? 1.0f : ((v < 0.0f) ? -1.0f : 0.0f);
        orow[(size_t)oi * SS] = res;
    }
}

// ============================ launch ================================================

extern "C" void kernel_launch(void* const* d_in, const int* in_sizes, int n_in,
                              void* d_out, int out_size, void* d_ws, size_t ws_size,
                              hipStream_t stream) {
    const float* x    = (const float*)d_in[0];
    const float* wgt  = (const float*)d_in[1];
    const float* bias = (const float*)d_in[2];
    float* out = (float*)d_out;

    const size_t wsB4_bytes = (size_t)OO * BROW4;               // 294,912
    const size_t xs4_bytes  = (size_t)NB * PH * PW * PIX4;      // 13,778,944
    if (ws_size >= wsB4_bytes + xs4_bytes) {
        uint8_t* wsB4 = (uint8_t*)d_ws;
        uint8_t* xs4  = (uint8_t*)d_ws + wsB4_bytes;
        pack_xs4_kernel<<<dim3(HH, NB), 256, 0, stream>>>(x, xs4);
        pack_wsB4_kernel<<<dim3(OO), 128, 0, stream>>>(wgt, wsB4);
        const int n_blocks = NB * SS / 128;                     // 784 (BN = whole N)
        bconv_mfma_kernel<<<dim3(n_blocks), 512, 0, stream>>>(xs4, wsB4, bias, out);
    } else {
        // fallback: proven popcount path (R4)
        size_t px_bytes = (size_t)NB * CWN * SPAD * 8;
        size_t pw_off   = px_bytes;
        size_t pw_bytes = (size_t)OO * 9 * CWN * 8;
        size_t k_off    = pw_off + pw_bytes;
        uint64_t* px  = (uint64_t*)d_ws;
        uint64_t* pwb = (uint64_t*)((char*)d_ws + pw_off);
        int*      kt  = (int*)((char*)d_ws + k_off);
        dim3 gpx((SPAD + 255) / 256, CWN, NB);
        pack_x_kernel<<<gpx, 256, 0, stream>>>(x, px);
        int nwords = OO * 9 * CWN;
        pack_w_kernel<<<dim3((nwords + 3) / 4), 256, 0, stream>>>(wgt, pwb);
        build_k_kernel<<<dim3(1), 256, 0, stream>>>(pwb, kt);
        dim3 gcv(NB * SS / 256, OO / 32, 1);
        bconv_kernel<<<gcv, 256, 0, stream>>>(px, pwb, kt, bias, out);
    }
}

// Round 16
// 76.866 us; speedup vs baseline: 1.5935x; 1.0609x over previous
//
#include <hip/hip_runtime.h>
#include <stdint.h>

typedef __attribute__((ext_vector_type(4))) int   i32x4;
typedef __attribute__((ext_vector_type(8))) int   i32x8;
typedef __attribute__((ext_vector_type(4))) float f32x4;

// BinaryConv: out = sign(conv2d(sign(x), sign(w), pad=1) + bias)
// R16: MX-FP4 implicit GEMM (verified bit-exact R14/R15, ~30us) + pack_xs4 v3:
// 2 rows/block => 448B-aligned 448B segments per channel (line-efficient), 512 thr,
// batched loads (7 in flight), LDS [256][113] transpose (2-way banks, free).

#define NB 32
#define CC 256
#define HH 56
#define WW 56
#define OO 256
#define PH 58
#define PW 58
#define SS (HH*WW)      // 3136
#define KTOT 2304
#define BROW4 1152      // wsB4 row bytes: 9 taps x 128 ch-pairs
#define PIX4  128       // xs4 bytes per pixel
#define LTP 113         // LDS transpose pitch (2 rows x 56 + 1)

// ---- async global->LDS, 16B per lane; dest = wave-uniform base + lane*16 -----------
__device__ __forceinline__ void gload16(const void* g, void* l) {
    const __attribute__((address_space(1))) void* gp =
        reinterpret_cast<const __attribute__((address_space(1))) void*>(
            reinterpret_cast<uintptr_t>(g));
    __attribute__((address_space(3))) void* lp =
        reinterpret_cast<__attribute__((address_space(3))) void*>(
            static_cast<uintptr_t>(static_cast<uint32_t>(reinterpret_cast<uintptr_t>(l))));
    __builtin_amdgcn_global_load_lds(gp, lp, 16, 0, 0);
}

#define WAITVM(N) asm volatile("s_waitcnt vmcnt(" #N ")" ::: "memory")
#define WAITLGKM0() asm volatile("s_waitcnt lgkmcnt(0)" ::: "memory")

__device__ __forceinline__ uint8_t nib4(float v) {
    return (v > 0.f) ? 0x2u : ((v < 0.f) ? 0xAu : 0x0u);   // e2m1 +1 / -1 / 0
}

// ============================ pack kernels ==========================================

// xs4: [n][ph][pw][c/2] fp4-pair bytes, border pixels = 0.
// Block = (h-pair, n), 512 threads. Phase 1: channels' 2-row segments (448 B,
// 448B-aligned) read as float4 runs, batched 7-deep; nibbles -> LDS [c][row*56+w],
// pitch 113. Phase 2: coalesced u32 pair-byte writes; borders zeroed in-kernel.
__global__ __launch_bounds__(512) void pack_xs4_kernel(const float* __restrict__ x,
                                                       uint8_t* __restrict__ xs4) {
    __shared__ uint8_t lt[256 * LTP];     // 28928 B
    const int t  = threadIdx.x;           // 0..511
    const int h0 = blockIdx.x * 2;        // 0,2,..,54
    const int n  = blockIdx.y;
    const float* xbase = x + (size_t)n * CC * SS + h0 * WW;

    // 256 ch x 28 float4 (2 rows) = 7168 quads, 14/thread, in two 7-deep batches
#pragma unroll
    for (int half = 0; half < 2; ++half) {
        float4 v[7];
#pragma unroll
        for (int i = 0; i < 7; ++i) {
            int f = (half * 7 + i) * 512 + t;
            int c = f / 28, q = f - c * 28;
            v[i] = *(const float4*)(xbase + (size_t)c * SS + q * 4);
        }
#pragma unroll
        for (int i = 0; i < 7; ++i) {
            int f = (half * 7 + i) * 512 + t;
            int c = f / 28, q = f - c * 28;
            uint8_t* lrow = &lt[c * LTP + 4 * q];
            lrow[0] = nib4(v[i].x);
            lrow[1] = nib4(v[i].y);
            lrow[2] = nib4(v[i].z);
            lrow[3] = nib4(v[i].w);
        }
    }
    __syncthreads();

    // interior pixels of rows h0, h0+1: 2 x 56 x 32 u32 = 3584
    for (int ot = t; ot < 2 * 56 * 32; ot += 512) {
        int k4  = ot & 31;                // u32 within pixel (8 channels)
        int idx = ot >> 5;                // 0..111 = row*56 + pw-1
        int row = idx / 56;
        int pwl = idx - row * 56;
        uint32_t r = 0;
#pragma unroll
        for (int b = 0; b < 4; ++b) {
            uint32_t lo = lt[(8 * k4 + 2 * b)     * LTP + idx];
            uint32_t hi = lt[(8 * k4 + 2 * b + 1) * LTP + idx];
            r |= ((lo | (hi << 4)) & 0xFFu) << (8 * b);
        }
        uint32_t* orow32 = (uint32_t*)(xs4 + (((size_t)n * PH + (h0 + row + 1)) * PW) * PIX4);
        orow32[(pwl + 1) * 32 + k4] = r;
    }
    // border pixels pw=0 and pw=57 of both rows: 2 x 2 x 32 = 128 u32
    if (t < 128) {
        int row = t >> 6;
        int rem = t & 63;
        int pix = (rem < 32) ? 0 : (PW - 1);
        uint32_t* orow32 = (uint32_t*)(xs4 + (((size_t)n * PH + (h0 + row + 1)) * PW) * PIX4);
        orow32[pix * 32 + (rem & 31)] = 0u;
    }
    // border rows ph=0 and ph=57
    if (h0 == 0) {
        uint32_t* z = (uint32_t*)(xs4 + ((size_t)n * PH * PW) * PIX4);
        for (int i = t; i < PW * 32; i += 512) z[i] = 0u;
    }
    if (h0 == HH - 2) {
        uint32_t* z = (uint32_t*)(xs4 + (((size_t)n * PH + (PH - 1)) * PW) * PIX4);
        for (int i = t; i < PW * 32; i += 512) z[i] = 0u;
    }
}

// wsB4: [o][t][c/2] fp4-pair bytes (row = 1152 B)
__global__ __launch_bounds__(128) void pack_wsB4_kernel(const float* __restrict__ wgt,
                                                        uint8_t* __restrict__ wsB4) {
    int j = threadIdx.x;           // channel pair
    int o = blockIdx.x;
    const float* s0 = wgt + ((size_t)o * CC + 2 * j) * 9;
    const float* s1 = wgt + ((size_t)o * CC + 2 * j + 1) * 9;
#pragma unroll
    for (int t = 0; t < 9; ++t)
        wsB4[(size_t)o * BROW4 + t * 128 + j] = (uint8_t)(nib4(s0[t]) | (nib4(s1[t]) << 4));
}

// ============================ MFMA GEMM (MX-FP4, verified R14/R15) ==================
// Block = 8 waves (2M x 4N), 512 threads. Tile 128 px x 256 ch, K-tile = 128 elems
// (64 B/row). 18 K-tiles. LDS: A[2][128*64]=16KB + B[2][256*64]=32KB dbuf;
// STAGE = 3 gload16/thread. Counted vmcnt(3). Swizzle bit-exact since R9.

#define STAGE(BUF, KT) do {                                                  \
    const int _t = (KT) >> 1, _q = (KT) & 1;                                 \
    const uint32_t _at = (uint32_t)(((_t / 3) * PW + (_t % 3)) * PIX4 + _q * 64); \
    const uint32_t _bt = (uint32_t)(_t * 128 + _q * 64);                     \
    gload16(xs4 + (apb0 + _at), &Asm[BUF][wid * 1024]);                      \
    gload16(wsB4 + (bpb0 + _bt), &Bsm[BUF][wid * 1024]);                     \
    gload16(wsB4 + (bpb1 + _bt), &Bsm[BUF][8192 + wid * 1024]);              \
} while (0)

#define COMPUTE(BUF) do {                                                    \
    const uint8_t* _Ab = &Asm[BUF][0];                                       \
    const uint8_t* _Bb = &Bsm[BUF][0];                                       \
    i32x4 af[4], bf[4];                                                      \
    _Pragma("unroll")                                                        \
    for (int _s = 0; _s < 4; ++_s) af[_s] = *(const i32x4*)(_Ab + swzA[_s]); \
    _Pragma("unroll")                                                        \
    for (int _u = 0; _u < 4; ++_u) bf[_u] = *(const i32x4*)(_Bb + swzB[_u]); \
    WAITLGKM0();                                                             \
    __builtin_amdgcn_sched_barrier(0);                                      \
    _Pragma("unroll")                                                        \
    for (int _s = 0; _s < 4; ++_s) {                                         \
        i32x8 _a8 = (i32x8){af[_s].x, af[_s].y, af[_s].z, af[_s].w, 0, 0, 0, 0}; \
        _Pragma("unroll")                                                    \
        for (int _u = 0; _u < 4; ++_u) {                                     \
            i32x8 _b8 = (i32x8){bf[_u].x, bf[_u].y, bf[_u].z, bf[_u].w, 0, 0, 0, 0}; \
            acc[_s][_u] = __builtin_amdgcn_mfma_scale_f32_16x16x128_f8f6f4(  \
                _a8, _b8, acc[_s][_u], 4, 4, 0, 0x7F7F7F7F, 0, 0x7F7F7F7F);  \
        }                                                                    \
    }                                                                        \
} while (0)

__global__ __launch_bounds__(512, 3) void bconv_mfma_kernel(const uint8_t* __restrict__ xs4,
                                                            const uint8_t* __restrict__ wsB4,
                                                            const float* __restrict__ bias,
                                                            float* __restrict__ out) {
    __shared__ __align__(16) uint8_t Asm[2][128 * 64];   // 8 KB each
    __shared__ __align__(16) uint8_t Bsm[2][256 * 64];   // 16 KB each

    const int m   = blockIdx.x;            // 0..783 M-tile (BN = whole N)
    const int tid = threadIdx.x;           // 0..511
    const int l   = tid & 63;
    const int wid = tid >> 6;              // 0..7
    const int lg  = l >> 4;                // k-group 0..3 (32 fp4 elems each)
    const int lr  = l & 15;                // row (A) / col (B,C)
    const int wm  = wid & 1, wn = wid >> 1;   // 2 x 4 wave grid

    const int M0 = m * 128;

    // ---- staging addresses: thread handles row tid>>2, chunk tid&3 -----------------
    const int srow0 = tid >> 2;                       // 0..127
    const int g16   = (((tid & 3) ^ ((tid >> 3) & 3)) << 4);
    uint32_t apb0, bpb0, bpb1;
    {
        int p0 = M0 + srow0;
        int n0 = p0 / SS, sp0 = p0 - n0 * SS, h0 = sp0 / WW, w0 = sp0 - h0 * WW;
        apb0 = (uint32_t)(((n0 * PH + h0) * PW + w0) * PIX4 + g16);
        bpb0 = (uint32_t)((srow0) * BROW4 + g16);
        bpb1 = (uint32_t)((128 + srow0) * BROW4 + g16);
    }

    // ---- ds_read offsets (swizzled) ------------------------------------------------
    const int swz16 = ((lg ^ ((lr >> 1) & 3)) << 4);
    int swzA[4], swzB[4];
#pragma unroll
    for (int s = 0; s < 4; ++s) swzA[s] = (wm * 64 + s * 16 + lr) * 64 + swz16;
#pragma unroll
    for (int u = 0; u < 4; ++u) swzB[u] = (wn * 64 + u * 16 + lr) * 64 + swz16;

    f32x4 acc[4][4];
#pragma unroll
    for (int s = 0; s < 4; ++s)
#pragma unroll
        for (int u = 0; u < 4; ++u)
            acc[s][u] = (f32x4){0.f, 0.f, 0.f, 0.f};

    // ---- K-loop: 18 tiles of K=128, dbuf, counted vmcnt ----------------------------
    STAGE(0, 0);
    int cur = 0;
#pragma unroll 1
    for (int kt = 0; kt < 17; ++kt) {
        STAGE(cur ^ 1, kt + 1);            // 6 outstanding
        WAITVM(3);                         // tile kt landed; kt+1 stays in flight
        __builtin_amdgcn_s_barrier();
        COMPUTE(cur);
        WAITLGKM0();
        __builtin_amdgcn_sched_barrier(0);
        __builtin_amdgcn_s_barrier();      // gates next STAGE's overwrite of cur
        cur ^= 1;
    }
    WAITVM(0);
    __builtin_amdgcn_s_barrier();
    COMPUTE(cur);

    // ---- epilogue: C/D col=lr, row=lg*4+reg (verified, shape-determined) -----------
    float bo[4];
#pragma unroll
    for (int u = 0; u < 4; ++u) bo[u] = bias[wn * 64 + u * 16 + lr];

#pragma unroll
    for (int s = 0; s < 4; ++s) {
        int pst = M0 + wm * 64 + s * 16 + lg * 4;
        int n   = pst / SS;
        int sp  = pst - n * SS;
#pragma unroll
        for (int u = 0; u < 4; ++u) {
            f32x4 a = acc[s][u];
            int o = wn * 64 + u * 16 + lr;
            float v0 = a.x + bo[u];
            float v1 = a.y + bo[u];
            float v2 = a.z + bo[u];
            float v3 = a.w + bo[u];
            float4 r4;
            r4.x = (v0 > 0.f) ? 1.f : ((v0 < 0.f) ? -1.f : 0.f);
            r4.y = (v1 > 0.f) ? 1.f : ((v1 < 0.f) ? -1.f : 0.f);
            r4.z = (v2 > 0.f) ? 1.f : ((v2 < 0.f) ? -1.f : 0.f);
            r4.w = (v3 > 0.f) ? 1.f : ((v3 < 0.f) ? -1.f : 0.f);
            *(float4*)(out + ((size_t)(n * OO + o)) * SS + sp) = r4;
        }
    }
}

// ============================ fallback popcount path (R4, 163 us) ===================

#define SPAD (PH*PW)
#define CWN  4

__global__ __launch_bounds__(256) void pack_x_kernel(const float* __restrict__ x,
                                                     uint64_t* __restrict__ px) {
    int tid = threadIdx.x;
    int sp  = blockIdx.x * 256 + tid;
    int cw  = blockIdx.y;
    int n   = blockIdx.z;
    if (sp >= SPAD) return;
    int ph = sp / PW, pw_ = sp % PW;
    uint64_t* dst = px + (((size_t)n * CWN + cw) * SPAD + sp);
    if (ph == 0 || ph == PH - 1 || pw_ == 0 || pw_ == PW - 1) { *dst = 0ull; return; }
    int h = ph - 1, w = pw_ - 1;
    const float* src = x + ((size_t)(n * CC + cw * 64)) * SS + (h * WW + w);
    uint32_t lo = 0u, hi = 0u;
#pragma unroll
    for (int j = 0; j < 32; ++j) { float v = src[(size_t)j * SS];        lo |= (v > 0.0f ? 1u : 0u) << j; }
#pragma unroll
    for (int j = 0; j < 32; ++j) { float v = src[(size_t)(j + 32) * SS]; hi |= (v > 0.0f ? 1u : 0u) << j; }
    *dst = ((uint64_t)hi << 32) | (uint64_t)lo;
}

__global__ __launch_bounds__(256) void pack_w_kernel(const float* __restrict__ wgt,
                                                     uint64_t* __restrict__ pwb) {
    int lane = threadIdx.x & 63;
    int wave = threadIdx.x >> 6;
    int wi   = blockIdx.x * 4 + wave;
    if (wi >= OO * 9 * CWN) return;
    int o = wi / 36, rem = wi % 36, t = rem >> 2, cw = rem & 3;
    int c = cw * 64 + lane;
    float v = wgt[(size_t)(o * CC + c) * 9 + t];
    uint64_t m = __ballot(v > 0.0f);
    if (lane == 0) pwb[wi] = m;
}

__global__ __launch_bounds__(256) void build_k_kernel(const uint64_t* __restrict__ pwb,
                                                      int* __restrict__ ktab) {
    int o = threadIdx.x;
    int pops[9];
#pragma unroll
    for (int t = 0; t < 9; ++t) {
        int p = 0;
#pragma unroll
        for (int cw = 0; cw < 4; ++cw) p += __popcll(pwb[o * 36 + t * 4 + cw]);
        pops[t] = p;
    }
#pragma unroll
    for (int cls = 0; cls < 9; ++cls) {
        int vf = cls / 3, hf = cls % 3;
        int K = 9 * CC;
#pragma unroll
        for (int t = 0; t < 9; ++t) {
            int r = t / 3, k = t % 3;
            bool inv = (vf == 1 && r == 0) || (vf == 2 && r == 2) ||
                       (hf == 1 && k == 0) || (hf == 2 && k == 2);
            if (inv) K -= (CC - 2 * pops[t]);
        }
        ktab[cls * OO + o] = K;
    }
}

__global__ __launch_bounds__(256, 4) void bconv_kernel(const uint64_t* __restrict__ px,
                                                       const uint64_t* __restrict__ pwb,
                                                       const int* __restrict__ ktab,
                                                       const float* __restrict__ bias,
                                                       float* __restrict__ out) {
    int g = blockIdx.x * 256 + threadIdx.x;
    int n = g / SS;
    int sid = g - n * SS;
    int obase = blockIdx.y * 32;
    int h = sid / WW, w = sid - h * WW;
    int vf = (h == 0) ? 1 : ((h == HH - 1) ? 2 : 0);
    int hf = (w == 0) ? 1 : ((w == WW - 1) ? 2 : 0);
    const int* krow = ktab + (vf * 3 + hf) * OO + obase;
    const uint64_t* pb = px + (size_t)n * CWN * SPAD + h * PW + w;
    const uint32_t* wb = (const uint32_t*)pwb + (size_t)obase * 72;
    uint32_t acc[32];
#pragma unroll
    for (int i = 0; i < 32; ++i) acc[i] = 0u;
#pragma unroll 1
    for (int r = 0; r < 3; ++r) {
#pragma unroll 1
        for (int k = 0; k < 3; ++k) {
            int off = r * PW + k;
            uint64_t q0 = pb[off];
            uint64_t q1 = pb[SPAD + off];
            uint64_t q2 = pb[2 * SPAD + off];
            uint64_t q3 = pb[3 * SPAD + off];
            uint32_t pa0 = (uint32_t)q0, pa1 = (uint32_t)(q0 >> 32);
            uint32_t pa2 = (uint32_t)q1, pa3 = (uint32_t)(q1 >> 32);
            uint32_t pa4 = (uint32_t)q2, pa5 = (uint32_t)(q2 >> 32);
            uint32_t pa6 = (uint32_t)q3, pa7 = (uint32_t)(q3 >> 32);
            int t8 = (r * 3 + k) * 8;
#pragma unroll
            for (int oi = 0; oi < 32; ++oi) {
                const uint32_t* wv = wb + oi * 72 + t8;
                uint32_t a = acc[oi];
                a = __popc(pa0 ^ wv[0]) + a;
                a = __popc(pa1 ^ wv[1]) + a;
                a = __popc(pa2 ^ wv[2]) + a;
                a = __popc(pa3 ^ wv[3]) + a;
                a = __popc(pa4 ^ wv[4]) + a;
                a = __popc(pa5 ^ wv[5]) + a;
                a = __popc(pa6 ^ wv[6]) + a;
                a = __popc(pa7 ^ wv[7]) + a;
                acc[oi] = a;
            }
        }
    }
    float* orow = out + ((size_t)(n * OO + obase)) * SS + sid;
#pragma unroll
    for (int oi = 0; oi < 32; ++oi) {
        int s = krow[oi] - 2 * (int)acc[oi];
        float v = (float)s + bias[obase + oi];
        float res = (v > 0.0f) ? 1.0f : ((v < 0.0f) ? -1.0f : 0.0f);
        orow[(size_t)oi * SS] = res;
    }
}

// ============================ launch ================================================

extern "C" void kernel_launch(void* const* d_in, const int* in_sizes, int n_in,
                              void* d_out, int out_size, void* d_ws, size_t ws_size,
                              hipStream_t stream) {
    const float* x    = (const float*)d_in[0];
    const float* wgt  = (const float*)d_in[1];
    const float* bias = (const float*)d_in[2];
    float* out = (float*)d_out;

    const size_t wsB4_bytes = (size_t)OO * BROW4;               // 294,912
    const size_t xs4_bytes  = (size_t)NB * PH * PW * PIX4;      // 13,778,944
    if (ws_size >= wsB4_bytes + xs4_bytes) {
        uint8_t* wsB4 = (uint8_t*)d_ws;
        uint8_t* xs4  = (uint8_t*)d_ws + wsB4_bytes;
        pack_xs4_kernel<<<dim3(HH / 2, NB), 512, 0, stream>>>(x, xs4);
        pack_wsB4_kernel<<<dim3(OO), 128, 0, stream>>>(wgt, wsB4);
        const int n_blocks = NB * SS / 128;                     // 784 (BN = whole N)
        bconv_mfma_kernel<<<dim3(n_blocks), 512, 0, stream>>>(xs4, wsB4, bias, out);
    } else {
        // fallback: proven popcount path (R4)
        size_t px_bytes = (size_t)NB * CWN * SPAD * 8;
        size_t pw_off   = px_bytes;
        size_t pw_bytes = (size_t)OO * 9 * CWN * 8;
        size_t k_off    = pw_off + pw_bytes;
        uint64_t* px  = (uint64_t*)d_ws;
        uint64_t* pwb = (uint64_t*)((char*)d_ws + pw_off);
        int*      kt  = (int*)((char*)d_ws + k_off);
        dim3 gpx((SPAD + 255) / 256, CWN, NB);
        pack_x_kernel<<<gpx, 256, 0, stream>>>(x, px);
        int nwords = OO * 9 * CWN;
        pack_w_kernel<<<dim3((nwords + 3) / 4), 256, 0, stream>>>(wgt, pwb);
        build_k_kernel<<<dim3(1), 256, 0, stream>>>(pwb, kt);
        dim3 gcv(NB * SS / 256, OO / 32, 1);
        bconv_kernel<<<gcv, 256, 0, stream>>>(px, pwb, kt, bias, out);
    }
}